// Round 7
// baseline (153.412 us; speedup 1.0000x reference)
//
#include <hip/hip_runtime.h>
#include <math.h>

typedef __attribute__((ext_vector_type(8)))  short short8;
typedef __attribute__((ext_vector_type(16))) float f32x16;

#define B_  16
#define C_  256
#define N_  256
#define O_  256
#define T_  8192
#define L_  64
#define NC_ 128

__device__ inline unsigned short f2bf(float x) {
    unsigned u = __float_as_uint(x);
    u += 0x7fff + ((u >> 16) & 1);
    return (unsigned short)(u >> 16);
}
__device__ inline float bf2f(unsigned short h) {
    return __uint_as_float(((unsigned)h) << 16);
}
__device__ inline unsigned cvtpk(float a, float b) {   // {lo:bf16(a), hi:bf16(b)}
    unsigned r;
    asm("v_cvt_pk_bf16_f32 %0, %1, %2" : "=v"(r) : "v"(a), "v"(b));
    return r;
}
__device__ inline f32x16 zero16() {
    f32x16 z;
    #pragma unroll
    for (int i = 0; i < 16; ++i) z[i] = 0.f;
    return z;
}

// ---------------------------------------------------------------------------
// prep: Ad, AL=Ad^64, MFMA b-fragment streams for Bd and C.
//   idx = (((kk*8 + nt)*2 + s)*64 + l)*8 + j
// ---------------------------------------------------------------------------
__global__ __launch_bounds__(256) void k_prep(
    const float* __restrict__ raw_lambda, const float* __restrict__ B_c,
    const float* __restrict__ Cmat,
    float* __restrict__ Ad, float* __restrict__ AL,
    unsigned short* __restrict__ BdKf, unsigned short* __restrict__ CKf)
{
    const int r = blockIdx.x;
    const int t = threadIdx.x;
    const int kk = r >> 5, ri = r & 31;
    const int s = ri >> 4, hi = (ri >> 3) & 1, j = ri & 7;
    const int nt = t >> 5, l = (hi << 5) | (t & 31);
    const int idx = (((kk * 8 + nt) * 2 + s) * 64 + l) * 8 + j;

    if (blockIdx.y == 0) {
        const float x  = raw_lambda[t];
        const float sp = (x > 20.f) ? x : log1pf(expf(x));
        const float lam = -sp;
        const float ad  = expf(lam);
        const float factor = (fabsf(lam) > 1e-6f) ? (ad - 1.f) / lam : 1.f;
        if (r == 0) {
            Ad[t] = ad;
            float al = ad;
            #pragma unroll
            for (int i = 0; i < 6; ++i) al *= al;
            AL[t] = al;
        }
        BdKf[idx] = f2bf(B_c[r * N_ + t] * factor);
    } else {
        CKf[idx] = f2bf(Cmat[r * O_ + t]);
    }
}

// B-frag direct-from-L2 load (lane-linear stream, coalesced 1 KB/wave-inst)
#define LDFRAG(MAT, kk, buf) { \
    _Pragma("unroll") \
    for (int q_ = 0; q_ < 2; ++q_) \
        _Pragma("unroll") \
        for (int s_ = 0; s_ < 2; ++s_) \
            fb[buf][q_ * 2 + s_] = *(const short8*)( \
                (MAT) + ((((kk) * 8 + 2 * w + q_) * 2 + s_) * 64 + l) * 8); }

// ---------------------------------------------------------------------------
// Fused kernel: per (k,b) chunk — GEMM1 (X in regs), publish p_last (agent
// scope), decoupled look-back for the carry, scan, GEMM2 -> y. One pass.
// ---------------------------------------------------------------------------
__global__ __launch_bounds__(256, 2) void k_fused(
    const float* __restrict__ u,
    const unsigned short* __restrict__ BdKf, const unsigned short* __restrict__ CKf,
    const float* __restrict__ Ad, const float* __restrict__ AL,
    unsigned* __restrict__ flags, unsigned* __restrict__ partU,
    int* __restrict__ ticket, float* __restrict__ y)
{
    __shared__ __align__(16) unsigned short xs[16896]; // u-tile, then X image, then states
    __shared__ int vid_s;

    const int tid = threadIdx.x;
    const int w = tid >> 6, l = tid & 63, lo = l & 31, hi = l >> 5;

    if (tid == 0) vid_s = atomicAdd(ticket, 1);
    __syncthreads();                                   // (1) vid visible
    const int vid = vid_s;
    const int b = vid & 15, k = vid >> 4;
    const int t0 = k * L_;
    const float* ub = u + (size_t)b * C_ * T_ + t0;

    const float adq0 = Ad[(2 * w + 0) * 32 + lo];
    const float adq1 = Ad[(2 * w + 1) * 32 + lo];

    // ---- stage u chunk: 16 float4 in flight, shfl-pack, swizzled [64][264] ----
    {
        float4 v[16];
        #pragma unroll
        for (int q = 0; q < 16; ++q) {
            const int i = q * 256 + tid, cl = i >> 4, t4 = i & 15;
            v[q] = *(const float4*)(ub + (size_t)cl * T_ + t4 * 4);
        }
        unsigned* ud = (unsigned*)xs;
        #pragma unroll
        for (int q = 0; q < 16; ++q) {
            const int i = q * 256 + tid, cl = i >> 4, t4 = i & 15;
            float4 a = v[q], p;
            p.x = __shfl_xor(a.x, 16); p.y = __shfl_xor(a.y, 16);
            p.z = __shfl_xor(a.z, 16); p.w = __shfl_xor(a.w, 16);
            const bool odd = (cl & 1) != 0;
            const float l0 = odd ? p.z : a.x, h0 = odd ? a.z : p.x;
            const float l1 = odd ? p.w : a.y, h1 = odd ? a.w : p.y;
            const int r0 = odd ? 2 : 0;
            const int nb = cl >> 3, jd = (cl >> 1) & 3;
            const int tA = 4 * t4 + r0, tB = tA + 1;
            const int xsw = (tA >> 3) & 3;
            ud[tA * 132 + (((nb ^ xsw) << 2) | jd)] = cvtpk(l0, h0);
            ud[tB * 132 + (((nb ^ xsw) << 2) | jd)] = cvtpk(l1, h1);
        }
    }
    __syncthreads();                                   // (2) u tile ready

    // ---- GEMM1: barrier-free; Bd frags direct from L2, 2-ahead prefetch ----
    f32x16 a00 = zero16(), a01 = zero16(), a10 = zero16(), a11 = zero16();
    {
        short8 fb[3][4];
        LDFRAG(BdKf, 0, 0)
        LDFRAG(BdKf, 1, 1)
        #pragma unroll
        for (int kk = 0; kk < 8; ++kk) {
            if (kk < 6) LDFRAG(BdKf, kk + 2, (kk + 2) % 3)
            #pragma unroll
            for (int s = 0; s < 2; ++s) {
                const int blk8 = kk * 4 + s * 2 + hi;
                const int tA2 = lo, tB2 = 32 + lo;
                const short8 fa0 = *(const short8*)(xs + tA2 * 264 + ((blk8 ^ ((tA2 >> 3) & 3)) << 3));
                const short8 fa1 = *(const short8*)(xs + tB2 * 264 + ((blk8 ^ ((tB2 >> 3) & 3)) << 3));
                const short8 fb0 = fb[kk % 3][0 * 2 + s];
                const short8 fb1 = fb[kk % 3][1 * 2 + s];
                a00 = __builtin_amdgcn_mfma_f32_32x32x16_bf16(fa0, fb0, a00, 0, 0, 0);
                a01 = __builtin_amdgcn_mfma_f32_32x32x16_bf16(fa0, fb1, a01, 0, 0, 0);
                a10 = __builtin_amdgcn_mfma_f32_32x32x16_bf16(fa1, fb0, a10, 0, 0, 0);
                a11 = __builtin_amdgcn_mfma_f32_32x32x16_bf16(fa1, fb1, a11, 0, 0, 0);
            }
        }
    }

    // ---- p_last in-register (row map: t = tt*32 + (reg&3) + 8*(reg>>2) + 4*hi) ----
    {
        float p[2];
        #pragma unroll
        for (int q = 0; q < 2; ++q) {
            const float ad = q ? adq1 : adq0;
            const float ad2 = ad * ad, ad4 = ad2 * ad2, ad8 = ad4 * ad4;
            const float ad16 = ad8 * ad8, ad32 = ad16 * ad16;
            float full[2];
            #pragma unroll
            for (int tt = 0; tt < 2; ++tt) {
                const f32x16 a = (tt == 0) ? (q == 0 ? a00 : a01)
                                           : (q == 0 ? a10 : a11);
                float v2[4];
                #pragma unroll
                for (int g = 0; g < 4; ++g)
                    v2[g] = fmaf(fmaf(fmaf(a[4*g], ad, a[4*g+1]), ad, a[4*g+2]), ad, a[4*g+3]);
                const float H = fmaf(fmaf(fmaf(v2[0], ad8, v2[1]), ad8, v2[2]), ad8, v2[3]);
                float P = hi ? H : H * ad4;
                P += __shfl_xor(P, 32);
                full[tt] = P;
            }
            p[q] = fmaf(full[0], ad32, full[1]);
        }
        if (hi == 0) {
            unsigned* dst = partU + (size_t)(b * 128 + k) * 256;
            __hip_atomic_store(dst + (2 * w + 0) * 32 + lo, __float_as_uint(p[0]),
                               __ATOMIC_RELAXED, __HIP_MEMORY_SCOPE_AGENT);
            __hip_atomic_store(dst + (2 * w + 1) * 32 + lo, __float_as_uint(p[1]),
                               __ATOMIC_RELAXED, __HIP_MEMORY_SCOPE_AGENT);
        }
    }
    __syncthreads();   // (3) part stores drained (vmcnt(0) before barrier) + xs reads done
    if (tid == 0)
        __hip_atomic_store(flags + b * 128 + k, 1u,
                           __ATOMIC_RELEASE, __HIP_MEMORY_SCOPE_AGENT);

    // ---- dump frags -> xs as X image (frag layout, dwords) ----
    {
        unsigned* Xd = (unsigned*)xs;
        #pragma unroll
        for (int f = 0; f < 4; ++f) {
            const f32x16 a = (f == 0) ? a00 : (f == 1) ? a01 : (f == 2) ? a10 : a11;
            unsigned dw[8];
            #pragma unroll
            for (int d = 0; d < 8; ++d)
                dw[d] = cvtpk(a[2 * d], a[2 * d + 1]);
            unsigned* base = Xd + w * 2048 + f * 512 + l * 4;
            *(int4*)(base)       = *(const int4*)&dw[0];
            *(int4*)(base + 256) = *(const int4*)&dw[4];
        }
    }
    __syncthreads();                                   // (4) X image ready

    // ---- gather this thread's column (n = tid) ----
    unsigned arr[2][2][8];   // [tt][h][dw]
    {
        const unsigned* xd = (const unsigned*)xs;
        const int w2 = tid >> 6, q2 = (tid >> 5) & 1, lo2 = tid & 31;
        #pragma unroll
        for (int tt = 0; tt < 2; ++tt)
            #pragma unroll
            for (int h2 = 0; h2 < 2; ++h2) {
                const unsigned* p = xd + w2 * 2048 + (tt * 2 + q2) * 512
                                       + (h2 * 32 + lo2) * 4;
                *(int4*)&arr[tt][h2][0] = *(const int4*)(p);
                *(int4*)&arr[tt][h2][4] = *(const int4*)(p + 256);
            }
    }

    // ---- decoupled look-back: carry = sum_{j<k} AL^(k-1-j) * part[j] ----
    float cur = 0.f;
    {
        if (tid < k) {
            const unsigned* fl = flags + b * 128 + tid;
            while (__hip_atomic_load(fl, __ATOMIC_RELAXED, __HIP_MEMORY_SCOPE_AGENT) == 0u)
                __builtin_amdgcn_s_sleep(1);
        }
        __syncthreads();                               // (5) all preds flagged; gathers done
        const float al = AL[tid];
        const unsigned* pU = partU + (size_t)b * 128 * 256 + tid;
        #pragma unroll 16
        for (int j = 0; j < k; ++j) {
            const float pv = __uint_as_float(
                __hip_atomic_load(pU + (size_t)j * 256,
                                  __ATOMIC_RELAXED, __HIP_MEMORY_SCOPE_AGENT));
            cur = fmaf(cur, al, pv);
        }
    }

    // ---- scan + write states [64][264] with col-block XOR swizzle ----
    {
        const float ad = Ad[tid];
        const int nb = tid >> 3, nl = tid & 7;
        float s = cur;
        #pragma unroll
        for (int tt = 0; tt < 2; ++tt)
            #pragma unroll
            for (int g = 0; g < 4; ++g)
                #pragma unroll
                for (int h2 = 0; h2 < 2; ++h2) {
                    const unsigned d0 = arr[tt][h2][2 * g];
                    const unsigned d1 = arr[tt][h2][2 * g + 1];
                    const int tb = tt * 32 + 8 * g + 4 * h2;
                    const int swz = (((nb ^ ((tb >> 3) & 3)) << 3) | nl);
                    s = fmaf(s, ad, bf2f((unsigned short)(d0 & 0xffff)));
                    xs[(tb + 0) * 264 + swz] = f2bf(s);
                    s = fmaf(s, ad, bf2f((unsigned short)(d0 >> 16)));
                    xs[(tb + 1) * 264 + swz] = f2bf(s);
                    s = fmaf(s, ad, bf2f((unsigned short)(d1 & 0xffff)));
                    xs[(tb + 2) * 264 + swz] = f2bf(s);
                    s = fmaf(s, ad, bf2f((unsigned short)(d1 >> 16)));
                    xs[(tb + 3) * 264 + swz] = f2bf(s);
                }
    }
    __syncthreads();                                   // (6) states ready

    // ---- GEMM2: barrier-free; C frags direct from L2, 2-ahead prefetch ----
    f32x16 c00 = zero16(), c01 = zero16(), c10 = zero16(), c11 = zero16();
    {
        short8 fb[3][4];
        LDFRAG(CKf, 0, 0)
        LDFRAG(CKf, 1, 1)
        #pragma unroll
        for (int kk = 0; kk < 8; ++kk) {
            if (kk < 6) LDFRAG(CKf, kk + 2, (kk + 2) % 3)
            #pragma unroll
            for (int s = 0; s < 2; ++s) {
                short8 fa[2];
                #pragma unroll
                for (int tt = 0; tt < 2; ++tt) {
                    const int t = tt * 32 + lo;
                    const int blk = (kk * 4 + s * 2 + hi) ^ ((t >> 3) & 3);
                    fa[tt] = *(const short8*)(xs + t * 264 + blk * 8);
                }
                const short8 fb0 = fb[kk % 3][0 * 2 + s];
                const short8 fb1 = fb[kk % 3][1 * 2 + s];
                c00 = __builtin_amdgcn_mfma_f32_32x32x16_bf16(fa[0], fb0, c00, 0, 0, 0);
                c01 = __builtin_amdgcn_mfma_f32_32x32x16_bf16(fa[0], fb1, c01, 0, 0, 0);
                c10 = __builtin_amdgcn_mfma_f32_32x32x16_bf16(fa[1], fb0, c10, 0, 0, 0);
                c11 = __builtin_amdgcn_mfma_f32_32x32x16_bf16(fa[1], fb1, c11, 0, 0, 0);
            }
        }
    }

    // ---- y store ----
    #pragma unroll
    for (int tt = 0; tt < 2; ++tt)
        #pragma unroll
        for (int q = 0; q < 2; ++q) {
            const f32x16 a = (tt == 0) ? (q == 0 ? c00 : c01) : (q == 0 ? c10 : c11);
            const int o = (2 * w + q) * 32 + lo;
            float* yo = y + ((size_t)b * O_ + o) * T_ + t0 + tt * 32 + hi * 4;
            #pragma unroll
            for (int g = 0; g < 4; ++g) {
                float4 vv;
                vv.x = a[g * 4 + 0]; vv.y = a[g * 4 + 1];
                vv.z = a[g * 4 + 2]; vv.w = a[g * 4 + 3];
                *(float4*)(yo + g * 8) = vv;
            }
        }
}

// ---------------------------------------------------------------------------
// ws layout (bytes):
//   0      ticket (int)            [zeroed per launch]
//   128    flags  (2048 u32)       [zeroed per launch]
//   8448   Ad     (256 f32)
//   9472   AL     (256 f32)
//   10496  partU  (128*16*256 u32 = 2 MB)
//   2107648 BdKf  (128 KB bf16 frag stream)
//   2238720 CKf   (128 KB)
// total ~2.37 MB
// ---------------------------------------------------------------------------
extern "C" void kernel_launch(void* const* d_in, const int* in_sizes, int n_in,
                              void* d_out, int out_size, void* d_ws, size_t ws_size,
                              hipStream_t stream)
{
    const float* u  = (const float*)d_in[0];
    const float* rl = (const float*)d_in[1];
    const float* Bc = (const float*)d_in[2];
    const float* Cm = (const float*)d_in[3];
    float* y  = (float*)d_out;
    char*  ws = (char*)d_ws;

    int*      ticket = (int*)(ws + 0);
    unsigned* flags  = (unsigned*)(ws + 128);
    float*    Ad     = (float*)(ws + 8448);
    float*    AL     = (float*)(ws + 9472);
    unsigned* partU  = (unsigned*)(ws + 10496);
    unsigned short* BdKf = (unsigned short*)(ws + 2107648);
    unsigned short* CKf  = (unsigned short*)(ws + 2238720);

    hipMemsetAsync(d_ws, 0, 8448, stream);   // ticket + flags
    k_prep <<<dim3(256, 2),   dim3(256), 0, stream>>>(rl, Bc, Cm, Ad, AL, BdKf, CKf);
    k_fused<<<dim3(NC_ * B_), dim3(256), 0, stream>>>(u, BdKf, CKf, Ad, AL,
                                                      flags, partU, ticket, y);
}

// Round 8
// 151.663 us; speedup vs baseline: 1.0115x; 1.0115x over previous
//
#include <hip/hip_runtime.h>
#include <math.h>

typedef __attribute__((ext_vector_type(8)))  short short8;
typedef __attribute__((ext_vector_type(16))) float f32x16;

#define B_  16
#define C_  256
#define N_  256
#define O_  256
#define T_  8192
#define L_  64
#define NC_ 128

__device__ inline unsigned short f2bf(float x) {
    unsigned u = __float_as_uint(x);
    u += 0x7fff + ((u >> 16) & 1);
    return (unsigned short)(u >> 16);
}
__device__ inline float bf2f(unsigned short h) {
    return __uint_as_float(((unsigned)h) << 16);
}
__device__ inline unsigned cvtpk(float a, float b) {   // {lo:bf16(a), hi:bf16(b)}
    unsigned r;
    asm("v_cvt_pk_bf16_f32 %0, %1, %2" : "=v"(r) : "v"(a), "v"(b));
    return r;
}
__device__ inline f32x16 zero16() {
    f32x16 z;
    #pragma unroll
    for (int i = 0; i < 16; ++i) z[i] = 0.f;
    return z;
}

// ---------------------------------------------------------------------------
// prep: Ad, AL=Ad^64, MFMA b-fragment streams for Bd and C.
//   idx = (((kk*8 + nt)*2 + s)*64 + l)*8 + j
// ---------------------------------------------------------------------------
__global__ __launch_bounds__(256) void k_prep(
    const float* __restrict__ raw_lambda, const float* __restrict__ B_c,
    const float* __restrict__ Cmat,
    float* __restrict__ Ad, float* __restrict__ AL,
    unsigned short* __restrict__ BdKf, unsigned short* __restrict__ CKf)
{
    const int r = blockIdx.x;
    const int t = threadIdx.x;
    const int kk = r >> 5, ri = r & 31;
    const int s = ri >> 4, hi = (ri >> 3) & 1, j = ri & 7;
    const int nt = t >> 5, l = (hi << 5) | (t & 31);
    const int idx = (((kk * 8 + nt) * 2 + s) * 64 + l) * 8 + j;

    if (blockIdx.y == 0) {
        const float x  = raw_lambda[t];
        const float sp = (x > 20.f) ? x : log1pf(expf(x));
        const float lam = -sp;
        const float ad  = expf(lam);
        const float factor = (fabsf(lam) > 1e-6f) ? (ad - 1.f) / lam : 1.f;
        if (r == 0) {
            Ad[t] = ad;
            float al = ad;
            #pragma unroll
            for (int i = 0; i < 6; ++i) al *= al;
            AL[t] = al;
        }
        BdKf[idx] = f2bf(B_c[r * N_ + t] * factor);
    } else {
        CKf[idx] = f2bf(Cmat[r * O_ + t]);
    }
}

// B-frag direct-from-L2 load (lane-linear stream, coalesced 1 KB/wave-inst)
#define LDFRAG(MAT, kk, buf) { \
    _Pragma("unroll") \
    for (int q_ = 0; q_ < 2; ++q_) \
        _Pragma("unroll") \
        for (int s_ = 0; s_ < 2; ++s_) \
            fb[buf][q_ * 2 + s_] = *(const short8*)( \
                (MAT) + ((((kk) * 8 + 2 * w + q_) * 2 + s_) * 64 + l) * 8); }

// ---------------------------------------------------------------------------
// Fused kernel: per (k,b) chunk — GEMM1 (X in regs), publish p_last (agent
// scope), batched deterministic look-back for the carry, scan, GEMM2 -> y.
// ---------------------------------------------------------------------------
__global__ __launch_bounds__(256, 2) void k_fused(
    const float* __restrict__ u,
    const unsigned short* __restrict__ BdKf, const unsigned short* __restrict__ CKf,
    const float* __restrict__ Ad, const float* __restrict__ AL,
    unsigned* __restrict__ flags, unsigned* __restrict__ partU,
    int* __restrict__ ticket, float* __restrict__ y)
{
    __shared__ __align__(16) unsigned short xs[16896]; // u-tile, then X image, then states
    __shared__ int vid_s;

    const int tid = threadIdx.x;
    const int w = tid >> 6, l = tid & 63, lo = l & 31, hi = l >> 5;

    if (tid == 0) vid_s = atomicAdd(ticket, 1);
    __syncthreads();                                   // (1) vid visible
    const int vid = vid_s;
    const int b = vid & 15, k = vid >> 4;
    const int t0 = k * L_;
    const float* ub = u + (size_t)b * C_ * T_ + t0;

    const float adq0 = Ad[(2 * w + 0) * 32 + lo];
    const float adq1 = Ad[(2 * w + 1) * 32 + lo];

    // ---- stage u chunk: 16 float4 in flight, shfl-pack, swizzled [64][264] ----
    {
        float4 v[16];
        #pragma unroll
        for (int q = 0; q < 16; ++q) {
            const int i = q * 256 + tid, cl = i >> 4, t4 = i & 15;
            v[q] = *(const float4*)(ub + (size_t)cl * T_ + t4 * 4);
        }
        unsigned* ud = (unsigned*)xs;
        #pragma unroll
        for (int q = 0; q < 16; ++q) {
            const int i = q * 256 + tid, cl = i >> 4, t4 = i & 15;
            float4 a = v[q], p;
            p.x = __shfl_xor(a.x, 16); p.y = __shfl_xor(a.y, 16);
            p.z = __shfl_xor(a.z, 16); p.w = __shfl_xor(a.w, 16);
            const bool odd = (cl & 1) != 0;
            const float l0 = odd ? p.z : a.x, h0 = odd ? a.z : p.x;
            const float l1 = odd ? p.w : a.y, h1 = odd ? a.w : p.y;
            const int r0 = odd ? 2 : 0;
            const int nb = cl >> 3, jd = (cl >> 1) & 3;
            const int tA = 4 * t4 + r0, tB = tA + 1;
            const int xsw = (tA >> 3) & 3;
            ud[tA * 132 + (((nb ^ xsw) << 2) | jd)] = cvtpk(l0, h0);
            ud[tB * 132 + (((nb ^ xsw) << 2) | jd)] = cvtpk(l1, h1);
        }
    }
    __syncthreads();                                   // (2) u tile ready

    // ---- GEMM1: barrier-free; Bd frags direct from L2, 2-ahead prefetch ----
    f32x16 a00 = zero16(), a01 = zero16(), a10 = zero16(), a11 = zero16();
    {
        short8 fb[3][4];
        LDFRAG(BdKf, 0, 0)
        LDFRAG(BdKf, 1, 1)
        #pragma unroll
        for (int kk = 0; kk < 8; ++kk) {
            if (kk < 6) LDFRAG(BdKf, kk + 2, (kk + 2) % 3)
            #pragma unroll
            for (int s = 0; s < 2; ++s) {
                const int blk8 = kk * 4 + s * 2 + hi;
                const int tA2 = lo, tB2 = 32 + lo;
                const short8 fa0 = *(const short8*)(xs + tA2 * 264 + ((blk8 ^ ((tA2 >> 3) & 3)) << 3));
                const short8 fa1 = *(const short8*)(xs + tB2 * 264 + ((blk8 ^ ((tB2 >> 3) & 3)) << 3));
                const short8 fb0 = fb[kk % 3][0 * 2 + s];
                const short8 fb1 = fb[kk % 3][1 * 2 + s];
                a00 = __builtin_amdgcn_mfma_f32_32x32x16_bf16(fa0, fb0, a00, 0, 0, 0);
                a01 = __builtin_amdgcn_mfma_f32_32x32x16_bf16(fa0, fb1, a01, 0, 0, 0);
                a10 = __builtin_amdgcn_mfma_f32_32x32x16_bf16(fa1, fb0, a10, 0, 0, 0);
                a11 = __builtin_amdgcn_mfma_f32_32x32x16_bf16(fa1, fb1, a11, 0, 0, 0);
            }
        }
    }

    // ---- p_last in-register (row map: t = tt*32 + (reg&3) + 8*(reg>>2) + 4*hi) ----
    {
        float p[2];
        #pragma unroll
        for (int q = 0; q < 2; ++q) {
            const float ad = q ? adq1 : adq0;
            const float ad2 = ad * ad, ad4 = ad2 * ad2, ad8 = ad4 * ad4;
            const float ad16 = ad8 * ad8, ad32 = ad16 * ad16;
            float full[2];
            #pragma unroll
            for (int tt = 0; tt < 2; ++tt) {
                const f32x16 a = (tt == 0) ? (q == 0 ? a00 : a01)
                                           : (q == 0 ? a10 : a11);
                float v2[4];
                #pragma unroll
                for (int g = 0; g < 4; ++g)
                    v2[g] = fmaf(fmaf(fmaf(a[4*g], ad, a[4*g+1]), ad, a[4*g+2]), ad, a[4*g+3]);
                const float H = fmaf(fmaf(fmaf(v2[0], ad8, v2[1]), ad8, v2[2]), ad8, v2[3]);
                float P = hi ? H : H * ad4;
                P += __shfl_xor(P, 32);
                full[tt] = P;
            }
            p[q] = fmaf(full[0], ad32, full[1]);
        }
        if (hi == 0) {
            unsigned* dst = partU + (size_t)(b * 128 + k) * 256;
            __hip_atomic_store(dst + (2 * w + 0) * 32 + lo, __float_as_uint(p[0]),
                               __ATOMIC_RELAXED, __HIP_MEMORY_SCOPE_AGENT);
            __hip_atomic_store(dst + (2 * w + 1) * 32 + lo, __float_as_uint(p[1]),
                               __ATOMIC_RELAXED, __HIP_MEMORY_SCOPE_AGENT);
        }
    }
    __syncthreads();   // (3) part stores drained (vmcnt(0) before barrier) + xs reads done
    if (tid == 0)
        __hip_atomic_store(flags + b * 128 + k, 1u,
                           __ATOMIC_RELEASE, __HIP_MEMORY_SCOPE_AGENT);

    // ---- dump frags -> xs as X image (frag layout, dwords) ----
    {
        unsigned* Xd = (unsigned*)xs;
        #pragma unroll
        for (int f = 0; f < 4; ++f) {
            const f32x16 a = (f == 0) ? a00 : (f == 1) ? a01 : (f == 2) ? a10 : a11;
            unsigned dw[8];
            #pragma unroll
            for (int d = 0; d < 8; ++d)
                dw[d] = cvtpk(a[2 * d], a[2 * d + 1]);
            unsigned* base = Xd + w * 2048 + f * 512 + l * 4;
            *(int4*)(base)       = *(const int4*)&dw[0];
            *(int4*)(base + 256) = *(const int4*)&dw[4];
        }
    }
    __syncthreads();                                   // (4) X image ready

    // ---- gather this thread's column (n = tid) ----
    unsigned arr[2][2][8];   // [tt][h][dw]
    {
        const unsigned* xd = (const unsigned*)xs;
        const int w2 = tid >> 6, q2 = (tid >> 5) & 1, lo2 = tid & 31;
        #pragma unroll
        for (int tt = 0; tt < 2; ++tt)
            #pragma unroll
            for (int h2 = 0; h2 < 2; ++h2) {
                const unsigned* p = xd + w2 * 2048 + (tt * 2 + q2) * 512
                                       + (h2 * 32 + lo2) * 4;
                *(int4*)&arr[tt][h2][0] = *(const int4*)(p);
                *(int4*)&arr[tt][h2][4] = *(const int4*)(p + 256);
            }
    }

    // ---- look-back: carry = sum_{j<k} AL^(k-1-j) * part[j], batched 32-wide.
    // Deterministic: fixed ascending-j Horner, same FP order as the 3-pass
    // phaseB. Tail loads beyond k stay in-buffer and are discarded by select.
    float cur = 0.f;
    {
        if (tid < k) {
            const unsigned* fl = flags + b * 128 + tid;
            while (__hip_atomic_load(fl, __ATOMIC_RELAXED, __HIP_MEMORY_SCOPE_AGENT) == 0u)
                __builtin_amdgcn_s_sleep(1);
        }
        __syncthreads();                               // (5) all preds flagged; gathers done
        const float al = AL[tid];
        const unsigned* pU = partU + (size_t)b * 128 * 256 + tid;
        const int nbat = (k + 31) >> 5;
        for (int jb = 0; jb < nbat; ++jb) {
            float pv[32];
            #pragma unroll
            for (int q = 0; q < 32; ++q) {
                const unsigned uv = __hip_atomic_load(
                    pU + (size_t)(jb * 32 + q) * 256,
                    __ATOMIC_RELAXED, __HIP_MEMORY_SCOPE_AGENT);
                pv[q] = __uint_as_float(uv);
            }
            #pragma unroll
            for (int q = 0; q < 32; ++q) {
                const float f = fmaf(cur, al, pv[q]);
                cur = (jb * 32 + q < k) ? f : cur;
            }
        }
    }

    // ---- scan + write states [64][264] with col-block XOR swizzle ----
    {
        const float ad = Ad[tid];
        const int nb = tid >> 3, nl = tid & 7;
        float s = cur;
        #pragma unroll
        for (int tt = 0; tt < 2; ++tt)
            #pragma unroll
            for (int g = 0; g < 4; ++g)
                #pragma unroll
                for (int h2 = 0; h2 < 2; ++h2) {
                    const unsigned d0 = arr[tt][h2][2 * g];
                    const unsigned d1 = arr[tt][h2][2 * g + 1];
                    const int tb = tt * 32 + 8 * g + 4 * h2;
                    const int swz = (((nb ^ ((tb >> 3) & 3)) << 3) | nl);
                    s = fmaf(s, ad, bf2f((unsigned short)(d0 & 0xffff)));
                    xs[(tb + 0) * 264 + swz] = f2bf(s);
                    s = fmaf(s, ad, bf2f((unsigned short)(d0 >> 16)));
                    xs[(tb + 1) * 264 + swz] = f2bf(s);
                    s = fmaf(s, ad, bf2f((unsigned short)(d1 & 0xffff)));
                    xs[(tb + 2) * 264 + swz] = f2bf(s);
                    s = fmaf(s, ad, bf2f((unsigned short)(d1 >> 16)));
                    xs[(tb + 3) * 264 + swz] = f2bf(s);
                }
    }
    __syncthreads();                                   // (6) states ready

    // ---- GEMM2: barrier-free; C frags direct from L2, 2-ahead prefetch ----
    f32x16 c00 = zero16(), c01 = zero16(), c10 = zero16(), c11 = zero16();
    {
        short8 fb[3][4];
        LDFRAG(CKf, 0, 0)
        LDFRAG(CKf, 1, 1)
        #pragma unroll
        for (int kk = 0; kk < 8; ++kk) {
            if (kk < 6) LDFRAG(CKf, kk + 2, (kk + 2) % 3)
            #pragma unroll
            for (int s = 0; s < 2; ++s) {
                short8 fa[2];
                #pragma unroll
                for (int tt = 0; tt < 2; ++tt) {
                    const int t = tt * 32 + lo;
                    const int blk = (kk * 4 + s * 2 + hi) ^ ((t >> 3) & 3);
                    fa[tt] = *(const short8*)(xs + t * 264 + blk * 8);
                }
                const short8 fb0 = fb[kk % 3][0 * 2 + s];
                const short8 fb1 = fb[kk % 3][1 * 2 + s];
                c00 = __builtin_amdgcn_mfma_f32_32x32x16_bf16(fa[0], fb0, c00, 0, 0, 0);
                c01 = __builtin_amdgcn_mfma_f32_32x32x16_bf16(fa[0], fb1, c01, 0, 0, 0);
                c10 = __builtin_amdgcn_mfma_f32_32x32x16_bf16(fa[1], fb0, c10, 0, 0, 0);
                c11 = __builtin_amdgcn_mfma_f32_32x32x16_bf16(fa[1], fb1, c11, 0, 0, 0);
            }
        }
    }

    // ---- y store ----
    #pragma unroll
    for (int tt = 0; tt < 2; ++tt)
        #pragma unroll
        for (int q = 0; q < 2; ++q) {
            const f32x16 a = (tt == 0) ? (q == 0 ? c00 : c01) : (q == 0 ? c10 : c11);
            const int o = (2 * w + q) * 32 + lo;
            float* yo = y + ((size_t)b * O_ + o) * T_ + t0 + tt * 32 + hi * 4;
            #pragma unroll
            for (int g = 0; g < 4; ++g) {
                float4 vv;
                vv.x = a[g * 4 + 0]; vv.y = a[g * 4 + 1];
                vv.z = a[g * 4 + 2]; vv.w = a[g * 4 + 3];
                *(float4*)(yo + g * 8) = vv;
            }
        }
}

// ---------------------------------------------------------------------------
// ws layout (bytes):
//   0      ticket (int)            [zeroed per launch]
//   128    flags  (2048 u32)       [zeroed per launch]
//   8448   Ad     (256 f32)
//   9472   AL     (256 f32)
//   10496  partU  (128*16*256 u32 = 2 MB)
//   2107648 BdKf  (128 KB bf16 frag stream)
//   2238720 CKf   (128 KB)
// ---------------------------------------------------------------------------
extern "C" void kernel_launch(void* const* d_in, const int* in_sizes, int n_in,
                              void* d_out, int out_size, void* d_ws, size_t ws_size,
                              hipStream_t stream)
{
    const float* u  = (const float*)d_in[0];
    const float* rl = (const float*)d_in[1];
    const float* Bc = (const float*)d_in[2];
    const float* Cm = (const float*)d_in[3];
    float* y  = (float*)d_out;
    char*  ws = (char*)d_ws;

    int*      ticket = (int*)(ws + 0);
    unsigned* flags  = (unsigned*)(ws + 128);
    float*    Ad     = (float*)(ws + 8448);
    float*    AL     = (float*)(ws + 9472);
    unsigned* partU  = (unsigned*)(ws + 10496);
    unsigned short* BdKf = (unsigned short*)(ws + 2107648);
    unsigned short* CKf  = (unsigned short*)(ws + 2238720);

    hipMemsetAsync(d_ws, 0, 8448, stream);   // ticket + flags
    k_prep <<<dim3(256, 2),   dim3(256), 0, stream>>>(rl, Bc, Cm, Ad, AL, BdKf, CKf);
    k_fused<<<dim3(NC_ * B_), dim3(256), 0, stream>>>(u, BdKf, CKf, Ad, AL,
                                                      flags, partU, ticket, y);
}

// Round 9
// 120.485 us; speedup vs baseline: 1.2733x; 1.2588x over previous
//
#include <hip/hip_runtime.h>
#include <math.h>

typedef __attribute__((ext_vector_type(4)))  float f32x4;
typedef __attribute__((ext_vector_type(8)))  short short8;
typedef __attribute__((ext_vector_type(16))) float f32x16;

#define B_  16
#define C_  256
#define N_  256
#define O_  256
#define T_  8192
#define L_  64
#define NC_ 128

// async global->LDS, 16B per lane; lds base wave-uniform (HW adds lane*16)
#define GLL16(gptr, lptr) \
  __builtin_amdgcn_global_load_lds((const __attribute__((address_space(1))) void*)(gptr), \
                                   (__attribute__((address_space(3))) void*)(lptr), 16, 0, 0)

__device__ inline unsigned short f2bf(float x) {
    unsigned u = __float_as_uint(x);
    u += 0x7fff + ((u >> 16) & 1);
    return (unsigned short)(u >> 16);
}
__device__ inline float bf2f(unsigned short h) {
    return __uint_as_float(((unsigned)h) << 16);
}
__device__ inline unsigned cvtpk(float a, float b) {   // {lo:bf16(a), hi:bf16(b)}
    unsigned r;
    asm("v_cvt_pk_bf16_f32 %0, %1, %2" : "=v"(r) : "v"(a), "v"(b));
    return r;
}
__device__ inline f32x16 zero16() {
    f32x16 z;
    #pragma unroll
    for (int i = 0; i < 16; ++i) z[i] = 0.f;
    return z;
}

// ---------------------------------------------------------------------------
// prep: Ad, AL=Ad^64, MFMA b-fragment streams for Bd and C.
//   idx = (((kk*8 + nt)*2 + s)*64 + l)*8 + j
// ---------------------------------------------------------------------------
__global__ __launch_bounds__(256) void k_prep(
    const float* __restrict__ raw_lambda, const float* __restrict__ B_c,
    const float* __restrict__ Cmat,
    float* __restrict__ Ad, float* __restrict__ AL,
    unsigned short* __restrict__ BdKf, unsigned short* __restrict__ CKf)
{
    const int r = blockIdx.x;
    const int t = threadIdx.x;
    const int kk = r >> 5, ri = r & 31;
    const int s = ri >> 4, hi = (ri >> 3) & 1, j = ri & 7;
    const int nt = t >> 5, l = (hi << 5) | (t & 31);
    const int idx = (((kk * 8 + nt) * 2 + s) * 64 + l) * 8 + j;

    if (blockIdx.y == 0) {
        const float x  = raw_lambda[t];
        const float sp = (x > 20.f) ? x : log1pf(expf(x));
        const float lam = -sp;
        const float ad  = expf(lam);
        const float factor = (fabsf(lam) > 1e-6f) ? (ad - 1.f) / lam : 1.f;
        if (r == 0) {
            Ad[t] = ad;
            float al = ad;
            #pragma unroll
            for (int i = 0; i < 6; ++i) al *= al;
            AL[t] = al;
        }
        BdKf[idx] = f2bf(B_c[r * N_ + t] * factor);
    } else {
        CKf[idx] = f2bf(Cmat[r * O_ + t]);
    }
}

// B-frag direct-from-L2 load (lane-linear stream, coalesced 1 KB/wave-inst)
#define LDFRAG(MAT, kk, buf) { \
    _Pragma("unroll") \
    for (int q_ = 0; q_ < 2; ++q_) \
        _Pragma("unroll") \
        for (int s_ = 0; s_ < 2; ++s_) \
            fb[buf][q_ * 2 + s_] = *(const short8*)( \
                (MAT) + ((((kk) * 8 + 2 * w + q_) * 2 + s_) * 64 + l) * 8); }

// ---------------------------------------------------------------------------
// Phase A (v9): launch_bounds(256,4); u staged in two 8-deep NT float4
// bursts; barrier-free GEMM1 with direct L2 B-frag loads.
// X stored to HBM from frags; p_last in-register.
// ---------------------------------------------------------------------------
__global__ __launch_bounds__(256, 4) void k_phaseA(
    const float* __restrict__ u, const unsigned short* __restrict__ BdKf,
    const float* __restrict__ Ad, float* __restrict__ p_last,
    unsigned short* __restrict__ X, int doX)
{
    __shared__ __align__(16) unsigned short ut[16896];   // [64][264] swizzled

    const int k = blockIdx.x, b = blockIdx.y;
    const int tid = threadIdx.x;
    const int w = tid >> 6, l = tid & 63, lo = l & 31, hi = l >> 5;
    const float* ub = u + (size_t)b * C_ * T_ + k * L_;

    const float adq0 = Ad[(2 * w + 0) * 32 + lo];
    const float adq1 = Ad[(2 * w + 1) * 32 + lo];

    // ---- stage u: two 8-deep nontemporal float4 bursts, shfl-pack ----
    {
        unsigned* ud = (unsigned*)ut;
        #pragma unroll
        for (int h = 0; h < 2; ++h) {
            f32x4 v[8];
            #pragma unroll
            for (int q = 0; q < 8; ++q) {
                const int i = (h * 8 + q) * 256 + tid, cl = i >> 4, t4 = i & 15;
                v[q] = __builtin_nontemporal_load(
                    (const f32x4*)(ub + (size_t)cl * T_ + t4 * 4));
            }
            #pragma unroll
            for (int q = 0; q < 8; ++q) {
                const int i = (h * 8 + q) * 256 + tid, cl = i >> 4, t4 = i & 15;
                const f32x4 a = v[q];
                f32x4 p;
                p[0] = __shfl_xor(a[0], 16); p[1] = __shfl_xor(a[1], 16);
                p[2] = __shfl_xor(a[2], 16); p[3] = __shfl_xor(a[3], 16);
                const bool odd = (cl & 1) != 0;
                const float l0 = odd ? p[2] : a[0], h0 = odd ? a[2] : p[0];
                const float l1 = odd ? p[3] : a[1], h1 = odd ? a[3] : p[1];
                const int r0 = odd ? 2 : 0;
                const int nb = cl >> 3, jd = (cl >> 1) & 3;
                const int tA = 4 * t4 + r0, tB = tA + 1;
                const int xsw = (tA >> 3) & 3;
                ud[tA * 132 + (((nb ^ xsw) << 2) | jd)] = cvtpk(l0, h0);
                ud[tB * 132 + (((nb ^ xsw) << 2) | jd)] = cvtpk(l1, h1);
            }
        }
    }
    __syncthreads();

    // ---- GEMM1: barrier-free; Bd frags direct from L2, 2-ahead prefetch ----
    f32x16 a00 = zero16(), a01 = zero16(), a10 = zero16(), a11 = zero16();
    {
        short8 fb[3][4];
        LDFRAG(BdKf, 0, 0)
        LDFRAG(BdKf, 1, 1)
        #pragma unroll
        for (int kk = 0; kk < 8; ++kk) {
            if (kk < 6) LDFRAG(BdKf, kk + 2, (kk + 2) % 3)
            #pragma unroll
            for (int s = 0; s < 2; ++s) {
                const int blk8 = kk * 4 + s * 2 + hi;
                const int tA2 = lo, tB2 = 32 + lo;
                const short8 fa0 = *(const short8*)(ut + tA2 * 264 + ((blk8 ^ ((tA2 >> 3) & 3)) << 3));
                const short8 fa1 = *(const short8*)(ut + tB2 * 264 + ((blk8 ^ ((tB2 >> 3) & 3)) << 3));
                const short8 fb0 = fb[kk % 3][0 * 2 + s];
                const short8 fb1 = fb[kk % 3][1 * 2 + s];
                a00 = __builtin_amdgcn_mfma_f32_32x32x16_bf16(fa0, fb0, a00, 0, 0, 0);
                a01 = __builtin_amdgcn_mfma_f32_32x32x16_bf16(fa0, fb1, a01, 0, 0, 0);
                a10 = __builtin_amdgcn_mfma_f32_32x32x16_bf16(fa1, fb0, a10, 0, 0, 0);
                a11 = __builtin_amdgcn_mfma_f32_32x32x16_bf16(fa1, fb1, a11, 0, 0, 0);
            }
        }
    }

    // ---- X store: packed bf16, frag layout, coalesced dwordx4 ----
    if (doX) {
        unsigned* Xd = (unsigned*)X + (size_t)(k * B_ + b) * 8192;
        #pragma unroll
        for (int f = 0; f < 4; ++f) {
            const f32x16 a = (f == 0) ? a00 : (f == 1) ? a01 : (f == 2) ? a10 : a11;
            unsigned dw[8];
            #pragma unroll
            for (int d = 0; d < 8; ++d)
                dw[d] = cvtpk(a[2 * d], a[2 * d + 1]);
            unsigned* base = Xd + w * 2048 + f * 512 + l * 4;
            *(int4*)(base)       = *(const int4*)&dw[0];
            *(int4*)(base + 256) = *(const int4*)&dw[4];
        }
    }

    // ---- p_last in-register (row map: t = tt*32 + (reg&3) + 8*(reg>>2) + 4*hi) ----
    {
        float p[2];
        #pragma unroll
        for (int q = 0; q < 2; ++q) {
            const float ad = q ? adq1 : adq0;
            const float ad2 = ad * ad, ad4 = ad2 * ad2, ad8 = ad4 * ad4;
            const float ad16 = ad8 * ad8, ad32 = ad16 * ad16;
            float full[2];
            #pragma unroll
            for (int tt = 0; tt < 2; ++tt) {
                const f32x16 a = (tt == 0) ? (q == 0 ? a00 : a01)
                                           : (q == 0 ? a10 : a11);
                float v2[4];
                #pragma unroll
                for (int g = 0; g < 4; ++g)
                    v2[g] = fmaf(fmaf(fmaf(a[4*g], ad, a[4*g+1]), ad, a[4*g+2]), ad, a[4*g+3]);
                const float H = fmaf(fmaf(fmaf(v2[0], ad8, v2[1]), ad8, v2[2]), ad8, v2[3]);
                float P = hi ? H : H * ad4;
                P += __shfl_xor(P, 32);
                full[tt] = P;
            }
            p[q] = fmaf(full[0], ad32, full[1]);
        }
        if (hi == 0) {
            float* dst = p_last + (size_t)(k * B_ + b) * N_;
            dst[(2 * w + 0) * 32 + lo] = p[0];
            dst[(2 * w + 1) * 32 + lo] = p[1];
        }
    }
}

// ---------------------------------------------------------------------------
// Phase B: carry scan over chunks, LDS-prefetched.
// ---------------------------------------------------------------------------
__global__ __launch_bounds__(256) void k_phaseB(
    const float* __restrict__ p_last, const float* __restrict__ AL,
    float* __restrict__ carry)
{
    __shared__ float buf[32 * 256];
    const int b = blockIdx.x, n = threadIdx.x;
    const float al = AL[n];
    float cur = 0.f;
    for (int kc = 0; kc < 4; ++kc) {
        __syncthreads();
        #pragma unroll
        for (int q = 0; q < 32; ++q)
            buf[q * 256 + n] = p_last[((size_t)(kc * 32 + q) * B_ + b) * N_ + n];
        __syncthreads();
        #pragma unroll
        for (int q = 0; q < 32; ++q) {
            carry[((size_t)(kc * 32 + q) * B_ + b) * N_ + n] = cur;
            cur = fmaf(cur, al, buf[q * 256 + n]);
        }
    }
}

// ---------------------------------------------------------------------------
// Phase C (v9): GLL16 X -> LDS (X should be L3-resident); column gather;
// scan -> swizzled states (in place); barrier-free GEMM2 with direct L2
// C-frag loads; nontemporal y stores (keep L3 for X/u).
// ---------------------------------------------------------------------------
__global__ __launch_bounds__(256, 4) void k_phaseC(
    const unsigned short* __restrict__ X, const unsigned short* __restrict__ CKf,
    const float* __restrict__ Ad, const float* __restrict__ carry,
    float* __restrict__ y)
{
    __shared__ __align__(16) unsigned short xs[16896];  // X image -> states [64][264]

    const int k = blockIdx.x, b = blockIdx.y;
    const int tid = threadIdx.x;
    const int w = tid >> 6, l = tid & 63, lo = l & 31, hi = l >> 5;
    const int t0 = k * L_;

    {
        const char* src = (const char*)X + (size_t)(k * B_ + b) * 32768;
        #pragma unroll
        for (int q = 0; q < 8; ++q)
            GLL16(src + q * 4096 + w * 1024 + (l << 4),
                  (char*)xs + q * 4096 + w * 1024);
    }
    const float cv = carry[(size_t)(k * B_ + b) * N_ + tid];
    const float ad = Ad[tid];
    __syncthreads();

    // gather this thread's column (n = tid) from frag-layout X
    unsigned arr[2][2][8];   // [tt][h][dw]
    {
        const unsigned* xd = (const unsigned*)xs;
        const int w2 = tid >> 6, q2 = (tid >> 5) & 1, lo2 = tid & 31;
        #pragma unroll
        for (int tt = 0; tt < 2; ++tt)
            #pragma unroll
            for (int h2 = 0; h2 < 2; ++h2) {
                const unsigned* p = xd + w2 * 2048 + (tt * 2 + q2) * 512
                                       + (h2 * 32 + lo2) * 4;
                *(int4*)&arr[tt][h2][0] = *(const int4*)(p);
                *(int4*)&arr[tt][h2][4] = *(const int4*)(p + 256);
            }
    }
    __syncthreads();   // all X reads done before states overwrite

    // scan + write states [64][264] with col-block XOR swizzle
    {
        const int nb = tid >> 3, nl = tid & 7;
        float s = cv;
        #pragma unroll
        for (int tt = 0; tt < 2; ++tt)
            #pragma unroll
            for (int g = 0; g < 4; ++g)
                #pragma unroll
                for (int h2 = 0; h2 < 2; ++h2) {
                    const unsigned d0 = arr[tt][h2][2 * g];
                    const unsigned d1 = arr[tt][h2][2 * g + 1];
                    const int tb = tt * 32 + 8 * g + 4 * h2;
                    const int swz = (((nb ^ ((tb >> 3) & 3)) << 3) | nl);
                    s = fmaf(s, ad, bf2f((unsigned short)(d0 & 0xffff)));
                    xs[(tb + 0) * 264 + swz] = f2bf(s);
                    s = fmaf(s, ad, bf2f((unsigned short)(d0 >> 16)));
                    xs[(tb + 1) * 264 + swz] = f2bf(s);
                    s = fmaf(s, ad, bf2f((unsigned short)(d1 & 0xffff)));
                    xs[(tb + 2) * 264 + swz] = f2bf(s);
                    s = fmaf(s, ad, bf2f((unsigned short)(d1 >> 16)));
                    xs[(tb + 3) * 264 + swz] = f2bf(s);
                }
    }
    __syncthreads();

    // ---- GEMM2: barrier-free; C-frags direct from L2, 2-ahead prefetch ----
    f32x16 c00 = zero16(), c01 = zero16(), c10 = zero16(), c11 = zero16();
    {
        short8 fb[3][4];
        LDFRAG(CKf, 0, 0)
        LDFRAG(CKf, 1, 1)
        #pragma unroll
        for (int kk = 0; kk < 8; ++kk) {
            if (kk < 6) LDFRAG(CKf, kk + 2, (kk + 2) % 3)
            #pragma unroll
            for (int s = 0; s < 2; ++s) {
                short8 fa[2];
                #pragma unroll
                for (int tt = 0; tt < 2; ++tt) {
                    const int t = tt * 32 + lo;
                    const int blk = (kk * 4 + s * 2 + hi) ^ ((t >> 3) & 3);
                    fa[tt] = *(const short8*)(xs + t * 264 + blk * 8);
                }
                const short8 fb0 = fb[kk % 3][0 * 2 + s];
                const short8 fb1 = fb[kk % 3][1 * 2 + s];
                c00 = __builtin_amdgcn_mfma_f32_32x32x16_bf16(fa[0], fb0, c00, 0, 0, 0);
                c01 = __builtin_amdgcn_mfma_f32_32x32x16_bf16(fa[0], fb1, c01, 0, 0, 0);
                c10 = __builtin_amdgcn_mfma_f32_32x32x16_bf16(fa[1], fb0, c10, 0, 0, 0);
                c11 = __builtin_amdgcn_mfma_f32_32x32x16_bf16(fa[1], fb1, c11, 0, 0, 0);
            }
        }
    }

    // ---- y store: nontemporal (write-once, keep L3 for X) ----
    #pragma unroll
    for (int tt = 0; tt < 2; ++tt)
        #pragma unroll
        for (int q = 0; q < 2; ++q) {
            const f32x16 a = (tt == 0) ? (q == 0 ? c00 : c01) : (q == 0 ? c10 : c11);
            const int o = (2 * w + q) * 32 + lo;
            float* yo = y + ((size_t)b * O_ + o) * T_ + t0 + tt * 32 + hi * 4;
            #pragma unroll
            for (int g = 0; g < 4; ++g) {
                f32x4 vv;
                vv[0] = a[g * 4 + 0]; vv[1] = a[g * 4 + 1];
                vv[2] = a[g * 4 + 2]; vv[3] = a[g * 4 + 3];
                __builtin_nontemporal_store(vv, (f32x4*)(yo + g * 8));
            }
        }
}

// ---------------------------------------------------------------------------
// Fallback Phase C (recompute GEMM1) — used only if ws too small.
// ---------------------------------------------------------------------------
__device__ __forceinline__ void gemm1_rc(
    const float* __restrict__ u, const unsigned short* __restrict__ BdKf,
    int b, int k, unsigned short* xs, unsigned short* ut, unsigned short* bb)
{
    const int tid = threadIdx.x;
    const int w = tid >> 6, l = tid & 63, lo = l & 31, hi = l >> 5;
    const int t0 = k * L_;
    f32x16 a00 = zero16(), a01 = zero16(), a10 = zero16(), a11 = zero16();
    for (int kk = 0; kk < 8; ++kk) {
        #pragma unroll
        for (int q = 0; q < 2; ++q) {
            const int i = q * 256 + tid, cl = i >> 4, t4 = i & 15;
            const float4 v = *(const float4*)(
                u + ((size_t)b * C_ + kk * 32 + cl) * T_ + t0 + t4 * 4);
            ut[(t4 * 4 + 0) * 40 + cl] = f2bf(v.x);
            ut[(t4 * 4 + 1) * 40 + cl] = f2bf(v.y);
            ut[(t4 * 4 + 2) * 40 + cl] = f2bf(v.z);
            ut[(t4 * 4 + 3) * 40 + cl] = f2bf(v.w);
        }
        {
            const unsigned short* src = BdKf + kk * 8192;
            #pragma unroll
            for (int q = 0; q < 4; ++q) {
                const int i16 = q * 256 + tid;
                *(int4*)(bb + i16 * 8) = *(const int4*)(src + i16 * 8);
            }
        }
        __syncthreads();
        #pragma unroll
        for (int s = 0; s < 2; ++s) {
            const short8 fa0 = *(const short8*)(ut + (0 * 32 + lo) * 40 + s * 16 + hi * 8);
            const short8 fa1 = *(const short8*)(ut + (1 * 32 + lo) * 40 + s * 16 + hi * 8);
            const short8 fb0 = *(const short8*)(bb + (((2 * w + 0) * 2 + s) * 64 + l) * 8);
            const short8 fb1 = *(const short8*)(bb + (((2 * w + 1) * 2 + s) * 64 + l) * 8);
            a00 = __builtin_amdgcn_mfma_f32_32x32x16_bf16(fa0, fb0, a00, 0, 0, 0);
            a01 = __builtin_amdgcn_mfma_f32_32x32x16_bf16(fa0, fb1, a01, 0, 0, 0);
            a10 = __builtin_amdgcn_mfma_f32_32x32x16_bf16(fa1, fb0, a10, 0, 0, 0);
            a11 = __builtin_amdgcn_mfma_f32_32x32x16_bf16(fa1, fb1, a11, 0, 0, 0);
        }
        __syncthreads();
    }
    #pragma unroll
    for (int tt = 0; tt < 2; ++tt)
        #pragma unroll
        for (int q = 0; q < 2; ++q) {
            const f32x16 a = (tt == 0) ? (q == 0 ? a00 : a01) : (q == 0 ? a10 : a11);
            const int n = (2 * w + q) * 32 + lo;
            #pragma unroll
            for (int g = 0; g < 4; ++g)
                #pragma unroll
                for (int p = 0; p < 2; ++p)
                    *(unsigned*)(xs + n * 66 + tt * 32 + hi * 4 + g * 8 + p * 2)
                        = f2bf(a[g * 4 + 2 * p]) | ((unsigned)f2bf(a[g * 4 + 2 * p + 1]) << 16);
        }
    __syncthreads();
}

__global__ __launch_bounds__(256) void k_phaseC_rc(
    const float* __restrict__ u, const unsigned short* __restrict__ BdKf,
    const unsigned short* __restrict__ CKf, const float* __restrict__ Ad,
    const float* __restrict__ carry, float* __restrict__ y)
{
    __shared__ __align__(16) unsigned short xs[16896];
    __shared__ __align__(16) unsigned short ut[2560];
    __shared__ __align__(16) unsigned short bb[8192];

    const int k = blockIdx.x, b = blockIdx.y;
    const int tid = threadIdx.x;
    const int w = tid >> 6, l = tid & 63, lo = l & 31, hi = l >> 5;
    const int t0 = k * L_;

    gemm1_rc(u, BdKf, b, k, xs, ut, bb);

    {
        const float a = Ad[tid];
        float s = carry[((size_t)k * B_ + b) * N_ + tid];
        float st[64];
        #pragma unroll
        for (int m = 0; m < 32; ++m) {
            const unsigned dw = *(const unsigned*)(xs + tid * 66 + 2 * m);
            s = fmaf(s, a, bf2f((unsigned short)(dw & 0xffff)));  st[2 * m] = s;
            s = fmaf(s, a, bf2f((unsigned short)(dw >> 16)));     st[2 * m + 1] = s;
        }
        __syncthreads();
        #pragma unroll
        for (int t = 0; t < 64; ++t) xs[t * 264 + tid] = f2bf(st[t]);
    }
    __syncthreads();

    f32x16 c00 = zero16(), c01 = zero16(), c10 = zero16(), c11 = zero16();
    for (int kk = 0; kk < 8; ++kk) {
        __syncthreads();
        {
            const unsigned short* src = CKf + kk * 8192;
            #pragma unroll
            for (int q = 0; q < 4; ++q) {
                const int i16 = q * 256 + tid;
                *(int4*)(bb + i16 * 8) = *(const int4*)(src + i16 * 8);
            }
        }
        __syncthreads();
        #pragma unroll
        for (int s = 0; s < 2; ++s) {
            const short8 fa0 = *(const short8*)(xs + (0 * 32 + lo) * 264 + kk * 32 + s * 16 + hi * 8);
            const short8 fa1 = *(const short8*)(xs + (1 * 32 + lo) * 264 + kk * 32 + s * 16 + hi * 8);
            const short8 fb0 = *(const short8*)(bb + (((2 * w + 0) * 2 + s) * 64 + l) * 8);
            const short8 fb1 = *(const short8*)(bb + (((2 * w + 1) * 2 + s) * 64 + l) * 8);
            c00 = __builtin_amdgcn_mfma_f32_32x32x16_bf16(fa0, fb0, c00, 0, 0, 0);
            c01 = __builtin_amdgcn_mfma_f32_32x32x16_bf16(fa0, fb1, c01, 0, 0, 0);
            c10 = __builtin_amdgcn_mfma_f32_32x32x16_bf16(fa1, fb0, c10, 0, 0, 0);
            c11 = __builtin_amdgcn_mfma_f32_32x32x16_bf16(fa1, fb1, c11, 0, 0, 0);
        }
    }

    #pragma unroll
    for (int tt = 0; tt < 2; ++tt)
        #pragma unroll
        for (int q = 0; q < 2; ++q) {
            const f32x16 a = (tt == 0) ? (q == 0 ? c00 : c01) : (q == 0 ? c10 : c11);
            const int o = (2 * w + q) * 32 + lo;
            float* yo = y + ((size_t)b * O_ + o) * T_ + t0 + tt * 32 + hi * 4;
            #pragma unroll
            for (int g = 0; g < 4; ++g) {
                float4 vv;
                vv.x = a[g * 4 + 0]; vv.y = a[g * 4 + 1];
                vv.z = a[g * 4 + 2]; vv.w = a[g * 4 + 3];
                *(float4*)(yo + g * 8) = vv;
            }
        }
}

// ---------------------------------------------------------------------------
extern "C" void kernel_launch(void* const* d_in, const int* in_sizes, int n_in,
                              void* d_out, int out_size, void* d_ws, size_t ws_size,
                              hipStream_t stream)
{
    const float* u  = (const float*)d_in[0];
    const float* rl = (const float*)d_in[1];
    const float* Bc = (const float*)d_in[2];
    const float* Cm = (const float*)d_in[3];
    float* y  = (float*)d_out;
    char*  ws = (char*)d_ws;

    float* Ad     = (float*)(ws + 0);
    float* AL     = (float*)(ws + 1024);
    float* p_last = (float*)(ws + 2048);
    float* carry  = (float*)(ws + 2048 + 2097152);
    unsigned short* BdKf = (unsigned short*)(ws + 2048 + 2 * 2097152);
    unsigned short* CKf  = (unsigned short*)(ws + 2048 + 2 * 2097152 + 131072);
    unsigned short* X    = (unsigned short*)(ws + 2048 + 2 * 2097152 + 2 * 131072);
    const size_t need = 2048 + 2ull * 2097152 + 2ull * 131072
                      + (size_t)NC_ * B_ * 32768;
    const int doX = (ws_size >= need) ? 1 : 0;

    k_prep  <<<dim3(256, 2),  dim3(256), 0, stream>>>(rl, Bc, Cm, Ad, AL, BdKf, CKf);
    k_phaseA<<<dim3(NC_, B_), dim3(256), 0, stream>>>(u, BdKf, Ad, p_last, X, doX);
    k_phaseB<<<dim3(B_),      dim3(256), 0, stream>>>(p_last, AL, carry);
    if (doX)
        k_phaseC<<<dim3(NC_, B_), dim3(256), 0, stream>>>(X, CKf, Ad, carry, y);
    else
        k_phaseC_rc<<<dim3(NC_, B_), dim3(256), 0, stream>>>(u, BdKf, CKf, Ad, carry, y);
}

// Round 10
// 107.773 us; speedup vs baseline: 1.4235x; 1.1180x over previous
//
#include <hip/hip_runtime.h>
#include <math.h>

typedef __attribute__((ext_vector_type(8)))  short short8;
typedef __attribute__((ext_vector_type(16))) float f32x16;

#define B_  16
#define C_  256
#define N_  256
#define O_  256
#define T_  8192
#define L_  64
#define NC_ 128

// async global->LDS, 16B per lane; lds base wave-uniform (HW adds lane*16)
#define GLL16(gptr, lptr) \
  __builtin_amdgcn_global_load_lds((const __attribute__((address_space(1))) void*)(gptr), \
                                   (__attribute__((address_space(3))) void*)(lptr), 16, 0, 0)

__device__ inline unsigned short f2bf(float x) {
    unsigned u = __float_as_uint(x);
    u += 0x7fff + ((u >> 16) & 1);
    return (unsigned short)(u >> 16);
}
__device__ inline float bf2f(unsigned short h) {
    return __uint_as_float(((unsigned)h) << 16);
}
__device__ inline unsigned cvtpk(float a, float b) {   // {lo:bf16(a), hi:bf16(b)}
    unsigned r;
    asm("v_cvt_pk_bf16_f32 %0, %1, %2" : "=v"(r) : "v"(a), "v"(b));
    return r;
}
__device__ inline f32x16 zero16() {
    f32x16 z;
    #pragma unroll
    for (int i = 0; i < 16; ++i) z[i] = 0.f;
    return z;
}

// ---------------------------------------------------------------------------
// prep: Ad, AL=Ad^64, MFMA b-fragment streams for Bd and C.
//   idx = (((kk*8 + nt)*2 + s)*64 + l)*8 + j
// ---------------------------------------------------------------------------
__global__ __launch_bounds__(256) void k_prep(
    const float* __restrict__ raw_lambda, const float* __restrict__ B_c,
    const float* __restrict__ Cmat,
    float* __restrict__ Ad, float* __restrict__ AL,
    unsigned short* __restrict__ BdKf, unsigned short* __restrict__ CKf)
{
    const int r = blockIdx.x;
    const int t = threadIdx.x;
    const int kk = r >> 5, ri = r & 31;
    const int s = ri >> 4, hi = (ri >> 3) & 1, j = ri & 7;
    const int nt = t >> 5, l = (hi << 5) | (t & 31);
    const int idx = (((kk * 8 + nt) * 2 + s) * 64 + l) * 8 + j;

    if (blockIdx.y == 0) {
        const float x  = raw_lambda[t];
        const float sp = (x > 20.f) ? x : log1pf(expf(x));
        const float lam = -sp;
        const float ad  = expf(lam);
        const float factor = (fabsf(lam) > 1e-6f) ? (ad - 1.f) / lam : 1.f;
        if (r == 0) {
            Ad[t] = ad;
            float al = ad;
            #pragma unroll
            for (int i = 0; i < 6; ++i) al *= al;
            AL[t] = al;
        }
        BdKf[idx] = f2bf(B_c[r * N_ + t] * factor);
    } else {
        CKf[idx] = f2bf(Cmat[r * O_ + t]);
    }
}

// B-frag direct-from-L2 load (lane-linear stream, coalesced 1 KB/wave-inst)
#define LDFRAG(MAT, kk, buf) { \
    _Pragma("unroll") \
    for (int q_ = 0; q_ < 2; ++q_) \
        _Pragma("unroll") \
        for (int s_ = 0; s_ < 2; ++s_) \
            fb[buf][q_ * 2 + s_] = *(const short8*)( \
                (MAT) + ((((kk) * 8 + 2 * w + q_) * 2 + s_) * 64 + l) * 8); }

// ---------------------------------------------------------------------------
// Phase A (v10 = v6 + launch_bounds(256,3)): 16-float4 u burst (one latency
// exposure), shfl-pack into swizzled [64][264] bf16 tile; barrier-free GEMM1
// with direct L2 B-frag loads (3-buf, 2-ahead). X to HBM; p_last in-register.
// ---------------------------------------------------------------------------
__global__ __launch_bounds__(256, 3) void k_phaseA(
    const float* __restrict__ u, const unsigned short* __restrict__ BdKf,
    const float* __restrict__ Ad, float* __restrict__ p_last,
    unsigned short* __restrict__ X, int doX)
{
    __shared__ __align__(16) unsigned short ut[16896];   // [64][264] swizzled

    const int k = blockIdx.x, b = blockIdx.y;
    const int tid = threadIdx.x;
    const int w = tid >> 6, l = tid & 63, lo = l & 31, hi = l >> 5;
    const float* ub = u + (size_t)b * C_ * T_ + k * L_;

    const float adq0 = Ad[(2 * w + 0) * 32 + lo];
    const float adq1 = Ad[(2 * w + 1) * 32 + lo];

    // ---- stage all of u: 16 float4 loads in flight, then shfl-pack ----
    {
        float4 v[16];
        #pragma unroll
        for (int q = 0; q < 16; ++q) {
            const int i = q * 256 + tid, cl = i >> 4, t4 = i & 15;
            v[q] = *(const float4*)(ub + (size_t)cl * T_ + t4 * 4);
        }
        unsigned* ud = (unsigned*)ut;
        #pragma unroll
        for (int q = 0; q < 16; ++q) {
            const int i = q * 256 + tid, cl = i >> 4, t4 = i & 15;
            float4 a = v[q], p;
            p.x = __shfl_xor(a.x, 16); p.y = __shfl_xor(a.y, 16);
            p.z = __shfl_xor(a.z, 16); p.w = __shfl_xor(a.w, 16);
            const bool odd = (cl & 1) != 0;
            const float l0 = odd ? p.z : a.x, h0 = odd ? a.z : p.x;
            const float l1 = odd ? p.w : a.y, h1 = odd ? a.w : p.y;
            const int r0 = odd ? 2 : 0;
            const int nb = cl >> 3, jd = (cl >> 1) & 3;
            const int tA = 4 * t4 + r0, tB = tA + 1;   // same 8-row stripe
            const int xsw = (tA >> 3) & 3;
            ud[tA * 132 + (((nb ^ xsw) << 2) | jd)] = cvtpk(l0, h0);
            ud[tB * 132 + (((nb ^ xsw) << 2) | jd)] = cvtpk(l1, h1);
        }
    }
    __syncthreads();

    // ---- GEMM1: barrier-free; Bd frags direct from L2, 2-ahead prefetch ----
    f32x16 a00 = zero16(), a01 = zero16(), a10 = zero16(), a11 = zero16();
    {
        short8 fb[3][4];
        LDFRAG(BdKf, 0, 0)
        LDFRAG(BdKf, 1, 1)
        #pragma unroll
        for (int kk = 0; kk < 8; ++kk) {
            if (kk < 6) LDFRAG(BdKf, kk + 2, (kk + 2) % 3)
            #pragma unroll
            for (int s = 0; s < 2; ++s) {
                const int blk8 = kk * 4 + s * 2 + hi;
                const int tA2 = lo, tB2 = 32 + lo;
                const short8 fa0 = *(const short8*)(ut + tA2 * 264 + ((blk8 ^ ((tA2 >> 3) & 3)) << 3));
                const short8 fa1 = *(const short8*)(ut + tB2 * 264 + ((blk8 ^ ((tB2 >> 3) & 3)) << 3));
                const short8 fb0 = fb[kk % 3][0 * 2 + s];
                const short8 fb1 = fb[kk % 3][1 * 2 + s];
                a00 = __builtin_amdgcn_mfma_f32_32x32x16_bf16(fa0, fb0, a00, 0, 0, 0);
                a01 = __builtin_amdgcn_mfma_f32_32x32x16_bf16(fa0, fb1, a01, 0, 0, 0);
                a10 = __builtin_amdgcn_mfma_f32_32x32x16_bf16(fa1, fb0, a10, 0, 0, 0);
                a11 = __builtin_amdgcn_mfma_f32_32x32x16_bf16(fa1, fb1, a11, 0, 0, 0);
            }
        }
    }

    // ---- X store: packed bf16, frag layout, coalesced dwordx4 ----
    if (doX) {
        unsigned* Xd = (unsigned*)X + (size_t)(k * B_ + b) * 8192;
        #pragma unroll
        for (int f = 0; f < 4; ++f) {
            const f32x16 a = (f == 0) ? a00 : (f == 1) ? a01 : (f == 2) ? a10 : a11;
            unsigned dw[8];
            #pragma unroll
            for (int d = 0; d < 8; ++d)
                dw[d] = cvtpk(a[2 * d], a[2 * d + 1]);
            unsigned* base = Xd + w * 2048 + f * 512 + l * 4;
            *(int4*)(base)       = *(const int4*)&dw[0];
            *(int4*)(base + 256) = *(const int4*)&dw[4];
        }
    }

    // ---- p_last in-register (row map: t = tt*32 + (reg&3) + 8*(reg>>2) + 4*hi) ----
    {
        float p[2];
        #pragma unroll
        for (int q = 0; q < 2; ++q) {
            const float ad = q ? adq1 : adq0;
            const float ad2 = ad * ad, ad4 = ad2 * ad2, ad8 = ad4 * ad4;
            const float ad16 = ad8 * ad8, ad32 = ad16 * ad16;
            float full[2];
            #pragma unroll
            for (int tt = 0; tt < 2; ++tt) {
                const f32x16 a = (tt == 0) ? (q == 0 ? a00 : a01)
                                           : (q == 0 ? a10 : a11);
                float v2[4];
                #pragma unroll
                for (int g = 0; g < 4; ++g)
                    v2[g] = fmaf(fmaf(fmaf(a[4*g], ad, a[4*g+1]), ad, a[4*g+2]), ad, a[4*g+3]);
                const float H = fmaf(fmaf(fmaf(v2[0], ad8, v2[1]), ad8, v2[2]), ad8, v2[3]);
                float P = hi ? H : H * ad4;
                P += __shfl_xor(P, 32);
                full[tt] = P;
            }
            p[q] = fmaf(full[0], ad32, full[1]);
        }
        if (hi == 0) {
            float* dst = p_last + (size_t)(k * B_ + b) * N_;
            dst[(2 * w + 0) * 32 + lo] = p[0];
            dst[(2 * w + 1) * 32 + lo] = p[1];
        }
    }
}

// ---------------------------------------------------------------------------
// Phase B: carry scan over chunks, LDS-prefetched.
// ---------------------------------------------------------------------------
__global__ __launch_bounds__(256) void k_phaseB(
    const float* __restrict__ p_last, const float* __restrict__ AL,
    float* __restrict__ carry)
{
    __shared__ float buf[32 * 256];
    const int b = blockIdx.x, n = threadIdx.x;
    const float al = AL[n];
    float cur = 0.f;
    for (int kc = 0; kc < 4; ++kc) {
        __syncthreads();
        #pragma unroll
        for (int q = 0; q < 32; ++q)
            buf[q * 256 + n] = p_last[((size_t)(kc * 32 + q) * B_ + b) * N_ + n];
        __syncthreads();
        #pragma unroll
        for (int q = 0; q < 32; ++q) {
            carry[((size_t)(kc * 32 + q) * B_ + b) * N_ + n] = cur;
            cur = fmaf(cur, al, buf[q * 256 + n]);
        }
    }
}

// ---------------------------------------------------------------------------
// Phase C (v10 = v6 + launch_bounds(256,3)): GLL16 X -> LDS; column gather;
// scan -> swizzled states (in place); barrier-free GEMM2 with direct L2
// C-frag loads.
// ---------------------------------------------------------------------------
__global__ __launch_bounds__(256, 3) void k_phaseC(
    const unsigned short* __restrict__ X, const unsigned short* __restrict__ CKf,
    const float* __restrict__ Ad, const float* __restrict__ carry,
    float* __restrict__ y)
{
    __shared__ __align__(16) unsigned short xs[16896];  // X image -> states [64][264]

    const int k = blockIdx.x, b = blockIdx.y;
    const int tid = threadIdx.x;
    const int w = tid >> 6, l = tid & 63, lo = l & 31, hi = l >> 5;
    const int t0 = k * L_;

    {
        const char* src = (const char*)X + (size_t)(k * B_ + b) * 32768;
        #pragma unroll
        for (int q = 0; q < 8; ++q)
            GLL16(src + q * 4096 + w * 1024 + (l << 4),
                  (char*)xs + q * 4096 + w * 1024);
    }
    const float cv = carry[(size_t)(k * B_ + b) * N_ + tid];
    const float ad = Ad[tid];
    __syncthreads();

    // gather this thread's column (n = tid) from frag-layout X
    unsigned arr[2][2][8];   // [tt][h][dw]
    {
        const unsigned* xd = (const unsigned*)xs;
        const int w2 = tid >> 6, q2 = (tid >> 5) & 1, lo2 = tid & 31;
        #pragma unroll
        for (int tt = 0; tt < 2; ++tt)
            #pragma unroll
            for (int h2 = 0; h2 < 2; ++h2) {
                const unsigned* p = xd + w2 * 2048 + (tt * 2 + q2) * 512
                                       + (h2 * 32 + lo2) * 4;
                *(int4*)&arr[tt][h2][0] = *(const int4*)(p);
                *(int4*)&arr[tt][h2][4] = *(const int4*)(p + 256);
            }
    }
    __syncthreads();   // all X reads done before states overwrite

    // scan + write states [64][264] with col-block XOR swizzle
    {
        const int nb = tid >> 3, nl = tid & 7;
        float s = cv;
        #pragma unroll
        for (int tt = 0; tt < 2; ++tt)
            #pragma unroll
            for (int g = 0; g < 4; ++g)
                #pragma unroll
                for (int h2 = 0; h2 < 2; ++h2) {
                    const unsigned d0 = arr[tt][h2][2 * g];
                    const unsigned d1 = arr[tt][h2][2 * g + 1];
                    const int tb = tt * 32 + 8 * g + 4 * h2;
                    const int swz = (((nb ^ ((tb >> 3) & 3)) << 3) | nl);
                    s = fmaf(s, ad, bf2f((unsigned short)(d0 & 0xffff)));
                    xs[(tb + 0) * 264 + swz] = f2bf(s);
                    s = fmaf(s, ad, bf2f((unsigned short)(d0 >> 16)));
                    xs[(tb + 1) * 264 + swz] = f2bf(s);
                    s = fmaf(s, ad, bf2f((unsigned short)(d1 & 0xffff)));
                    xs[(tb + 2) * 264 + swz] = f2bf(s);
                    s = fmaf(s, ad, bf2f((unsigned short)(d1 >> 16)));
                    xs[(tb + 3) * 264 + swz] = f2bf(s);
                }
    }
    __syncthreads();

    // ---- GEMM2: barrier-free; C-frags direct from L2, 2-ahead prefetch ----
    f32x16 c00 = zero16(), c01 = zero16(), c10 = zero16(), c11 = zero16();
    {
        short8 fb[3][4];
        LDFRAG(CKf, 0, 0)
        LDFRAG(CKf, 1, 1)
        #pragma unroll
        for (int kk = 0; kk < 8; ++kk) {
            if (kk < 6) LDFRAG(CKf, kk + 2, (kk + 2) % 3)
            #pragma unroll
            for (int s = 0; s < 2; ++s) {
                short8 fa[2];
                #pragma unroll
                for (int tt = 0; tt < 2; ++tt) {
                    const int t = tt * 32 + lo;
                    const int blk = (kk * 4 + s * 2 + hi) ^ ((t >> 3) & 3);
                    fa[tt] = *(const short8*)(xs + t * 264 + blk * 8);
                }
                const short8 fb0 = fb[kk % 3][0 * 2 + s];
                const short8 fb1 = fb[kk % 3][1 * 2 + s];
                c00 = __builtin_amdgcn_mfma_f32_32x32x16_bf16(fa[0], fb0, c00, 0, 0, 0);
                c01 = __builtin_amdgcn_mfma_f32_32x32x16_bf16(fa[0], fb1, c01, 0, 0, 0);
                c10 = __builtin_amdgcn_mfma_f32_32x32x16_bf16(fa[1], fb0, c10, 0, 0, 0);
                c11 = __builtin_amdgcn_mfma_f32_32x32x16_bf16(fa[1], fb1, c11, 0, 0, 0);
            }
        }
    }

    // ---- y store ----
    #pragma unroll
    for (int tt = 0; tt < 2; ++tt)
        #pragma unroll
        for (int q = 0; q < 2; ++q) {
            const f32x16 a = (tt == 0) ? (q == 0 ? c00 : c01) : (q == 0 ? c10 : c11);
            const int o = (2 * w + q) * 32 + lo;
            float* yo = y + ((size_t)b * O_ + o) * T_ + t0 + tt * 32 + hi * 4;
            #pragma unroll
            for (int g = 0; g < 4; ++g) {
                float4 vv;
                vv.x = a[g * 4 + 0]; vv.y = a[g * 4 + 1];
                vv.z = a[g * 4 + 2]; vv.w = a[g * 4 + 3];
                *(float4*)(yo + g * 8) = vv;
            }
        }
}

// ---------------------------------------------------------------------------
// Fallback Phase C (recompute GEMM1) — used only if ws too small.
// ---------------------------------------------------------------------------
__device__ __forceinline__ void gemm1_rc(
    const float* __restrict__ u, const unsigned short* __restrict__ BdKf,
    int b, int k, unsigned short* xs, unsigned short* ut, unsigned short* bb)
{
    const int tid = threadIdx.x;
    const int w = tid >> 6, l = tid & 63, lo = l & 31, hi = l >> 5;
    const int t0 = k * L_;
    f32x16 a00 = zero16(), a01 = zero16(), a10 = zero16(), a11 = zero16();
    for (int kk = 0; kk < 8; ++kk) {
        #pragma unroll
        for (int q = 0; q < 2; ++q) {
            const int i = q * 256 + tid, cl = i >> 4, t4 = i & 15;
            const float4 v = *(const float4*)(
                u + ((size_t)b * C_ + kk * 32 + cl) * T_ + t0 + t4 * 4);
            ut[(t4 * 4 + 0) * 40 + cl] = f2bf(v.x);
            ut[(t4 * 4 + 1) * 40 + cl] = f2bf(v.y);
            ut[(t4 * 4 + 2) * 40 + cl] = f2bf(v.z);
            ut[(t4 * 4 + 3) * 40 + cl] = f2bf(v.w);
        }
        {
            const unsigned short* src = BdKf + kk * 8192;
            #pragma unroll
            for (int q = 0; q < 4; ++q) {
                const int i16 = q * 256 + tid;
                *(int4*)(bb + i16 * 8) = *(const int4*)(src + i16 * 8);
            }
        }
        __syncthreads();
        #pragma unroll
        for (int s = 0; s < 2; ++s) {
            const short8 fa0 = *(const short8*)(ut + (0 * 32 + lo) * 40 + s * 16 + hi * 8);
            const short8 fa1 = *(const short8*)(ut + (1 * 32 + lo) * 40 + s * 16 + hi * 8);
            const short8 fb0 = *(const short8*)(bb + (((2 * w + 0) * 2 + s) * 64 + l) * 8);
            const short8 fb1 = *(const short8*)(bb + (((2 * w + 1) * 2 + s) * 64 + l) * 8);
            a00 = __builtin_amdgcn_mfma_f32_32x32x16_bf16(fa0, fb0, a00, 0, 0, 0);
            a01 = __builtin_amdgcn_mfma_f32_32x32x16_bf16(fa0, fb1, a01, 0, 0, 0);
            a10 = __builtin_amdgcn_mfma_f32_32x32x16_bf16(fa1, fb0, a10, 0, 0, 0);
            a11 = __builtin_amdgcn_mfma_f32_32x32x16_bf16(fa1, fb1, a11, 0, 0, 0);
        }
        __syncthreads();
    }
    #pragma unroll
    for (int tt = 0; tt < 2; ++tt)
        #pragma unroll
        for (int q = 0; q < 2; ++q) {
            const f32x16 a = (tt == 0) ? (q == 0 ? a00 : a01) : (q == 0 ? a10 : a11);
            const int n = (2 * w + q) * 32 + lo;
            #pragma unroll
            for (int g = 0; g < 4; ++g)
                #pragma unroll
                for (int p = 0; p < 2; ++p)
                    *(unsigned*)(xs + n * 66 + tt * 32 + hi * 4 + g * 8 + p * 2)
                        = f2bf(a[g * 4 + 2 * p]) | ((unsigned)f2bf(a[g * 4 + 2 * p + 1]) << 16);
        }
    __syncthreads();
}

__global__ __launch_bounds__(256) void k_phaseC_rc(
    const float* __restrict__ u, const unsigned short* __restrict__ BdKf,
    const unsigned short* __restrict__ CKf, const float* __restrict__ Ad,
    const float* __restrict__ carry, float* __restrict__ y)
{
    __shared__ __align__(16) unsigned short xs[16896];
    __shared__ __align__(16) unsigned short ut[2560];
    __shared__ __align__(16) unsigned short bb[8192];

    const int k = blockIdx.x, b = blockIdx.y;
    const int tid = threadIdx.x;
    const int w = tid >> 6, l = tid & 63, lo = l & 31, hi = l >> 5;
    const int t0 = k * L_;

    gemm1_rc(u, BdKf, b, k, xs, ut, bb);

    {
        const float a = Ad[tid];
        float s = carry[((size_t)k * B_ + b) * N_ + tid];
        float st[64];
        #pragma unroll
        for (int m = 0; m < 32; ++m) {
            const unsigned dw = *(const unsigned*)(xs + tid * 66 + 2 * m);
            s = fmaf(s, a, bf2f((unsigned short)(dw & 0xffff)));  st[2 * m] = s;
            s = fmaf(s, a, bf2f((unsigned short)(dw >> 16)));     st[2 * m + 1] = s;
        }
        __syncthreads();
        #pragma unroll
        for (int t = 0; t < 64; ++t) xs[t * 264 + tid] = f2bf(st[t]);
    }
    __syncthreads();

    f32x16 c00 = zero16(), c01 = zero16(), c10 = zero16(), c11 = zero16();
    for (int kk = 0; kk < 8; ++kk) {
        __syncthreads();
        {
            const unsigned short* src = CKf + kk * 8192;
            #pragma unroll
            for (int q = 0; q < 4; ++q) {
                const int i16 = q * 256 + tid;
                *(int4*)(bb + i16 * 8) = *(const int4*)(src + i16 * 8);
            }
        }
        __syncthreads();
        #pragma unroll
        for (int s = 0; s < 2; ++s) {
            const short8 fa0 = *(const short8*)(xs + (0 * 32 + lo) * 264 + kk * 32 + s * 16 + hi * 8);
            const short8 fa1 = *(const short8*)(xs + (1 * 32 + lo) * 264 + kk * 32 + s * 16 + hi * 8);
            const short8 fb0 = *(const short8*)(bb + (((2 * w + 0) * 2 + s) * 64 + l) * 8);
            const short8 fb1 = *(const short8*)(bb + (((2 * w + 1) * 2 + s) * 64 + l) * 8);
            c00 = __builtin_amdgcn_mfma_f32_32x32x16_bf16(fa0, fb0, c00, 0, 0, 0);
            c01 = __builtin_amdgcn_mfma_f32_32x32x16_bf16(fa0, fb1, c01, 0, 0, 0);
            c10 = __builtin_amdgcn_mfma_f32_32x32x16_bf16(fa1, fb0, c10, 0, 0, 0);
            c11 = __builtin_amdgcn_mfma_f32_32x32x16_bf16(fa1, fb1, c11, 0, 0, 0);
        }
    }

    #pragma unroll
    for (int tt = 0; tt < 2; ++tt)
        #pragma unroll
        for (int q = 0; q < 2; ++q) {
            const f32x16 a = (tt == 0) ? (q == 0 ? c00 : c01) : (q == 0 ? c10 : c11);
            const int o = (2 * w + q) * 32 + lo;
            float* yo = y + ((size_t)b * O_ + o) * T_ + t0 + tt * 32 + hi * 4;
            #pragma unroll
            for (int g = 0; g < 4; ++g) {
                float4 vv;
                vv.x = a[g * 4 + 0]; vv.y = a[g * 4 + 1];
                vv.z = a[g * 4 + 2]; vv.w = a[g * 4 + 3];
                *(float4*)(yo + g * 8) = vv;
            }
        }
}

// ---------------------------------------------------------------------------
extern "C" void kernel_launch(void* const* d_in, const int* in_sizes, int n_in,
                              void* d_out, int out_size, void* d_ws, size_t ws_size,
                              hipStream_t stream)
{
    const float* u  = (const float*)d_in[0];
    const float* rl = (const float*)d_in[1];
    const float* Bc = (const float*)d_in[2];
    const float* Cm = (const float*)d_in[3];
    float* y  = (float*)d_out;
    char*  ws = (char*)d_ws;

    float* Ad     = (float*)(ws + 0);
    float* AL     = (float*)(ws + 1024);
    float* p_last = (float*)(ws + 2048);
    float* carry  = (float*)(ws + 2048 + 2097152);
    unsigned short* BdKf = (unsigned short*)(ws + 2048 + 2 * 2097152);
    unsigned short* CKf  = (unsigned short*)(ws + 2048 + 2 * 2097152 + 131072);
    unsigned short* X    = (unsigned short*)(ws + 2048 + 2 * 2097152 + 2 * 131072);
    const size_t need = 2048 + 2ull * 2097152 + 2ull * 131072
                      + (size_t)NC_ * B_ * 32768;
    const int doX = (ws_size >= need) ? 1 : 0;

    k_prep  <<<dim3(256, 2),  dim3(256), 0, stream>>>(rl, Bc, Cm, Ad, AL, BdKf, CKf);
    k_phaseA<<<dim3(NC_, B_), dim3(256), 0, stream>>>(u, BdKf, Ad, p_last, X, doX);
    k_phaseB<<<dim3(B_),      dim3(256), 0, stream>>>(p_last, AL, carry);
    if (doX)
        k_phaseC<<<dim3(NC_, B_), dim3(256), 0, stream>>>(X, CKf, Ad, carry, y);
    else
        k_phaseC_rc<<<dim3(NC_, B_), dim3(256), 0, stream>>>(u, BdKf, CKf, Ad, carry, y);
}

// Round 11
// 102.613 us; speedup vs baseline: 1.4951x; 1.0503x over previous
//
#include <hip/hip_runtime.h>
#include <math.h>

typedef __attribute__((ext_vector_type(4)))  float f32x4;
typedef __attribute__((ext_vector_type(8)))  short short8;
typedef __attribute__((ext_vector_type(16))) float f32x16;

#define B_  16
#define C_  256
#define N_  256
#define O_  256
#define T_  8192
#define L_  64
#define NC_ 128

// async global->LDS, 16B per lane; lds base wave-uniform (HW adds lane*16)
#define GLL16(gptr, lptr) \
  __builtin_amdgcn_global_load_lds((const __attribute__((address_space(1))) void*)(gptr), \
                                   (__attribute__((address_space(3))) void*)(lptr), 16, 0, 0)

__device__ inline unsigned short f2bf(float x) {
    unsigned u = __float_as_uint(x);
    u += 0x7fff + ((u >> 16) & 1);
    return (unsigned short)(u >> 16);
}
__device__ inline float bf2f(unsigned short h) {
    return __uint_as_float(((unsigned)h) << 16);
}
__device__ inline unsigned cvtpk(float a, float b) {   // {lo:bf16(a), hi:bf16(b)}
    unsigned r;
    asm("v_cvt_pk_bf16_f32 %0, %1, %2" : "=v"(r) : "v"(a), "v"(b));
    return r;
}
__device__ inline f32x16 zero16() {
    f32x16 z;
    #pragma unroll
    for (int i = 0; i < 16; ++i) z[i] = 0.f;
    return z;
}

// ---------------------------------------------------------------------------
// prep: Ad, AL=Ad^64, MFMA b-fragment streams for Bd and C.
//   idx = (((kk*8 + nt)*2 + s)*64 + l)*8 + j
// ---------------------------------------------------------------------------
__global__ __launch_bounds__(256) void k_prep(
    const float* __restrict__ raw_lambda, const float* __restrict__ B_c,
    const float* __restrict__ Cmat,
    float* __restrict__ Ad, float* __restrict__ AL,
    unsigned short* __restrict__ BdKf, unsigned short* __restrict__ CKf)
{
    const int r = blockIdx.x;
    const int t = threadIdx.x;
    const int kk = r >> 5, ri = r & 31;
    const int s = ri >> 4, hi = (ri >> 3) & 1, j = ri & 7;
    const int nt = t >> 5, l = (hi << 5) | (t & 31);
    const int idx = (((kk * 8 + nt) * 2 + s) * 64 + l) * 8 + j;

    if (blockIdx.y == 0) {
        const float x  = raw_lambda[t];
        const float sp = (x > 20.f) ? x : log1pf(expf(x));
        const float lam = -sp;
        const float ad  = expf(lam);
        const float factor = (fabsf(lam) > 1e-6f) ? (ad - 1.f) / lam : 1.f;
        if (r == 0) {
            Ad[t] = ad;
            float al = ad;
            #pragma unroll
            for (int i = 0; i < 6; ++i) al *= al;
            AL[t] = al;
        }
        BdKf[idx] = f2bf(B_c[r * N_ + t] * factor);
    } else {
        CKf[idx] = f2bf(Cmat[r * O_ + t]);
    }
}

// B-frag direct-from-L2 load (lane-linear stream, coalesced 1 KB/wave-inst)
#define LDFRAG(MAT, kk, buf) { \
    _Pragma("unroll") \
    for (int q_ = 0; q_ < 2; ++q_) \
        _Pragma("unroll") \
        for (int s_ = 0; s_ < 2; ++s_) \
            fb[buf][q_ * 2 + s_] = *(const short8*)( \
                (MAT) + ((((kk) * 8 + 2 * w + q_) * 2 + s_) * 64 + l) * 8); }

// ---------------------------------------------------------------------------
// Phase A (v11 = v10 + NONTEMPORAL u loads): u is read-once — bypass L2/L3
// so the X image stays L3-resident for phaseC. Everything else unchanged.
// ---------------------------------------------------------------------------
__global__ __launch_bounds__(256, 3) void k_phaseA(
    const float* __restrict__ u, const unsigned short* __restrict__ BdKf,
    const float* __restrict__ Ad, float* __restrict__ p_last,
    unsigned short* __restrict__ X, int doX)
{
    __shared__ __align__(16) unsigned short ut[16896];   // [64][264] swizzled

    const int k = blockIdx.x, b = blockIdx.y;
    const int tid = threadIdx.x;
    const int w = tid >> 6, l = tid & 63, lo = l & 31, hi = l >> 5;
    const float* ub = u + (size_t)b * C_ * T_ + k * L_;

    const float adq0 = Ad[(2 * w + 0) * 32 + lo];
    const float adq1 = Ad[(2 * w + 1) * 32 + lo];

    // ---- stage all of u: 16 NT float4 loads in flight, then shfl-pack ----
    {
        f32x4 v[16];
        #pragma unroll
        for (int q = 0; q < 16; ++q) {
            const int i = q * 256 + tid, cl = i >> 4, t4 = i & 15;
            v[q] = __builtin_nontemporal_load(
                (const f32x4*)(ub + (size_t)cl * T_ + t4 * 4));
        }
        unsigned* ud = (unsigned*)ut;
        #pragma unroll
        for (int q = 0; q < 16; ++q) {
            const int i = q * 256 + tid, cl = i >> 4, t4 = i & 15;
            const f32x4 a = v[q];
            f32x4 p;
            p[0] = __shfl_xor(a[0], 16); p[1] = __shfl_xor(a[1], 16);
            p[2] = __shfl_xor(a[2], 16); p[3] = __shfl_xor(a[3], 16);
            const bool odd = (cl & 1) != 0;
            const float l0 = odd ? p[2] : a[0], h0 = odd ? a[2] : p[0];
            const float l1 = odd ? p[3] : a[1], h1 = odd ? a[3] : p[1];
            const int r0 = odd ? 2 : 0;
            const int nb = cl >> 3, jd = (cl >> 1) & 3;
            const int tA = 4 * t4 + r0, tB = tA + 1;   // same 8-row stripe
            const int xsw = (tA >> 3) & 3;
            ud[tA * 132 + (((nb ^ xsw) << 2) | jd)] = cvtpk(l0, h0);
            ud[tB * 132 + (((nb ^ xsw) << 2) | jd)] = cvtpk(l1, h1);
        }
    }
    __syncthreads();

    // ---- GEMM1: barrier-free; Bd frags direct from L2, 2-ahead prefetch ----
    f32x16 a00 = zero16(), a01 = zero16(), a10 = zero16(), a11 = zero16();
    {
        short8 fb[3][4];
        LDFRAG(BdKf, 0, 0)
        LDFRAG(BdKf, 1, 1)
        #pragma unroll
        for (int kk = 0; kk < 8; ++kk) {
            if (kk < 6) LDFRAG(BdKf, kk + 2, (kk + 2) % 3)
            #pragma unroll
            for (int s = 0; s < 2; ++s) {
                const int blk8 = kk * 4 + s * 2 + hi;
                const int tA2 = lo, tB2 = 32 + lo;
                const short8 fa0 = *(const short8*)(ut + tA2 * 264 + ((blk8 ^ ((tA2 >> 3) & 3)) << 3));
                const short8 fa1 = *(const short8*)(ut + tB2 * 264 + ((blk8 ^ ((tB2 >> 3) & 3)) << 3));
                const short8 fb0 = fb[kk % 3][0 * 2 + s];
                const short8 fb1 = fb[kk % 3][1 * 2 + s];
                a00 = __builtin_amdgcn_mfma_f32_32x32x16_bf16(fa0, fb0, a00, 0, 0, 0);
                a01 = __builtin_amdgcn_mfma_f32_32x32x16_bf16(fa0, fb1, a01, 0, 0, 0);
                a10 = __builtin_amdgcn_mfma_f32_32x32x16_bf16(fa1, fb0, a10, 0, 0, 0);
                a11 = __builtin_amdgcn_mfma_f32_32x32x16_bf16(fa1, fb1, a11, 0, 0, 0);
            }
        }
    }

    // ---- X store: packed bf16, frag layout, coalesced dwordx4 ----
    if (doX) {
        unsigned* Xd = (unsigned*)X + (size_t)(k * B_ + b) * 8192;
        #pragma unroll
        for (int f = 0; f < 4; ++f) {
            const f32x16 a = (f == 0) ? a00 : (f == 1) ? a01 : (f == 2) ? a10 : a11;
            unsigned dw[8];
            #pragma unroll
            for (int d = 0; d < 8; ++d)
                dw[d] = cvtpk(a[2 * d], a[2 * d + 1]);
            unsigned* base = Xd + w * 2048 + f * 512 + l * 4;
            *(int4*)(base)       = *(const int4*)&dw[0];
            *(int4*)(base + 256) = *(const int4*)&dw[4];
        }
    }

    // ---- p_last in-register (row map: t = tt*32 + (reg&3) + 8*(reg>>2) + 4*hi) ----
    {
        float p[2];
        #pragma unroll
        for (int q = 0; q < 2; ++q) {
            const float ad = q ? adq1 : adq0;
            const float ad2 = ad * ad, ad4 = ad2 * ad2, ad8 = ad4 * ad4;
            const float ad16 = ad8 * ad8, ad32 = ad16 * ad16;
            float full[2];
            #pragma unroll
            for (int tt = 0; tt < 2; ++tt) {
                const f32x16 a = (tt == 0) ? (q == 0 ? a00 : a01)
                                           : (q == 0 ? a10 : a11);
                float v2[4];
                #pragma unroll
                for (int g = 0; g < 4; ++g)
                    v2[g] = fmaf(fmaf(fmaf(a[4*g], ad, a[4*g+1]), ad, a[4*g+2]), ad, a[4*g+3]);
                const float H = fmaf(fmaf(fmaf(v2[0], ad8, v2[1]), ad8, v2[2]), ad8, v2[3]);
                float P = hi ? H : H * ad4;
                P += __shfl_xor(P, 32);
                full[tt] = P;
            }
            p[q] = fmaf(full[0], ad32, full[1]);
        }
        if (hi == 0) {
            float* dst = p_last + (size_t)(k * B_ + b) * N_;
            dst[(2 * w + 0) * 32 + lo] = p[0];
            dst[(2 * w + 1) * 32 + lo] = p[1];
        }
    }
}

// ---------------------------------------------------------------------------
// Phase B: carry scan over chunks, LDS-prefetched.
// ---------------------------------------------------------------------------
__global__ __launch_bounds__(256) void k_phaseB(
    const float* __restrict__ p_last, const float* __restrict__ AL,
    float* __restrict__ carry)
{
    __shared__ float buf[32 * 256];
    const int b = blockIdx.x, n = threadIdx.x;
    const float al = AL[n];
    float cur = 0.f;
    for (int kc = 0; kc < 4; ++kc) {
        __syncthreads();
        #pragma unroll
        for (int q = 0; q < 32; ++q)
            buf[q * 256 + n] = p_last[((size_t)(kc * 32 + q) * B_ + b) * N_ + n];
        __syncthreads();
        #pragma unroll
        for (int q = 0; q < 32; ++q) {
            carry[((size_t)(kc * 32 + q) * B_ + b) * N_ + n] = cur;
            cur = fmaf(cur, al, buf[q * 256 + n]);
        }
    }
}

// ---------------------------------------------------------------------------
// Phase C (v11 = v10 unchanged): GLL16 X -> LDS; column gather; scan ->
// swizzled states (in place); barrier-free GEMM2 with direct L2 C-frag loads.
// ---------------------------------------------------------------------------
__global__ __launch_bounds__(256, 3) void k_phaseC(
    const unsigned short* __restrict__ X, const unsigned short* __restrict__ CKf,
    const float* __restrict__ Ad, const float* __restrict__ carry,
    float* __restrict__ y)
{
    __shared__ __align__(16) unsigned short xs[16896];  // X image -> states [64][264]

    const int k = blockIdx.x, b = blockIdx.y;
    const int tid = threadIdx.x;
    const int w = tid >> 6, l = tid & 63, lo = l & 31, hi = l >> 5;
    const int t0 = k * L_;

    {
        const char* src = (const char*)X + (size_t)(k * B_ + b) * 32768;
        #pragma unroll
        for (int q = 0; q < 8; ++q)
            GLL16(src + q * 4096 + w * 1024 + (l << 4),
                  (char*)xs + q * 4096 + w * 1024);
    }
    const float cv = carry[(size_t)(k * B_ + b) * N_ + tid];
    const float ad = Ad[tid];
    __syncthreads();

    // gather this thread's column (n = tid) from frag-layout X
    unsigned arr[2][2][8];   // [tt][h][dw]
    {
        const unsigned* xd = (const unsigned*)xs;
        const int w2 = tid >> 6, q2 = (tid >> 5) & 1, lo2 = tid & 31;
        #pragma unroll
        for (int tt = 0; tt < 2; ++tt)
            #pragma unroll
            for (int h2 = 0; h2 < 2; ++h2) {
                const unsigned* p = xd + w2 * 2048 + (tt * 2 + q2) * 512
                                       + (h2 * 32 + lo2) * 4;
                *(int4*)&arr[tt][h2][0] = *(const int4*)(p);
                *(int4*)&arr[tt][h2][4] = *(const int4*)(p + 256);
            }
    }
    __syncthreads();   // all X reads done before states overwrite

    // scan + write states [64][264] with col-block XOR swizzle
    {
        const int nb = tid >> 3, nl = tid & 7;
        float s = cv;
        #pragma unroll
        for (int tt = 0; tt < 2; ++tt)
            #pragma unroll
            for (int g = 0; g < 4; ++g)
                #pragma unroll
                for (int h2 = 0; h2 < 2; ++h2) {
                    const unsigned d0 = arr[tt][h2][2 * g];
                    const unsigned d1 = arr[tt][h2][2 * g + 1];
                    const int tb = tt * 32 + 8 * g + 4 * h2;
                    const int swz = (((nb ^ ((tb >> 3) & 3)) << 3) | nl);
                    s = fmaf(s, ad, bf2f((unsigned short)(d0 & 0xffff)));
                    xs[(tb + 0) * 264 + swz] = f2bf(s);
                    s = fmaf(s, ad, bf2f((unsigned short)(d0 >> 16)));
                    xs[(tb + 1) * 264 + swz] = f2bf(s);
                    s = fmaf(s, ad, bf2f((unsigned short)(d1 & 0xffff)));
                    xs[(tb + 2) * 264 + swz] = f2bf(s);
                    s = fmaf(s, ad, bf2f((unsigned short)(d1 >> 16)));
                    xs[(tb + 3) * 264 + swz] = f2bf(s);
                }
    }
    __syncthreads();

    // ---- GEMM2: barrier-free; C-frags direct from L2, 2-ahead prefetch ----
    f32x16 c00 = zero16(), c01 = zero16(), c10 = zero16(), c11 = zero16();
    {
        short8 fb[3][4];
        LDFRAG(CKf, 0, 0)
        LDFRAG(CKf, 1, 1)
        #pragma unroll
        for (int kk = 0; kk < 8; ++kk) {
            if (kk < 6) LDFRAG(CKf, kk + 2, (kk + 2) % 3)
            #pragma unroll
            for (int s = 0; s < 2; ++s) {
                short8 fa[2];
                #pragma unroll
                for (int tt = 0; tt < 2; ++tt) {
                    const int t = tt * 32 + lo;
                    const int blk = (kk * 4 + s * 2 + hi) ^ ((t >> 3) & 3);
                    fa[tt] = *(const short8*)(xs + t * 264 + blk * 8);
                }
                const short8 fb0 = fb[kk % 3][0 * 2 + s];
                const short8 fb1 = fb[kk % 3][1 * 2 + s];
                c00 = __builtin_amdgcn_mfma_f32_32x32x16_bf16(fa[0], fb0, c00, 0, 0, 0);
                c01 = __builtin_amdgcn_mfma_f32_32x32x16_bf16(fa[0], fb1, c01, 0, 0, 0);
                c10 = __builtin_amdgcn_mfma_f32_32x32x16_bf16(fa[1], fb0, c10, 0, 0, 0);
                c11 = __builtin_amdgcn_mfma_f32_32x32x16_bf16(fa[1], fb1, c11, 0, 0, 0);
            }
        }
    }

    // ---- y store ----
    #pragma unroll
    for (int tt = 0; tt < 2; ++tt)
        #pragma unroll
        for (int q = 0; q < 2; ++q) {
            const f32x16 a = (tt == 0) ? (q == 0 ? c00 : c01) : (q == 0 ? c10 : c11);
            const int o = (2 * w + q) * 32 + lo;
            float* yo = y + ((size_t)b * O_ + o) * T_ + t0 + tt * 32 + hi * 4;
            #pragma unroll
            for (int g = 0; g < 4; ++g) {
                float4 vv;
                vv.x = a[g * 4 + 0]; vv.y = a[g * 4 + 1];
                vv.z = a[g * 4 + 2]; vv.w = a[g * 4 + 3];
                *(float4*)(yo + g * 8) = vv;
            }
        }
}

// ---------------------------------------------------------------------------
// Fallback Phase C (recompute GEMM1) — used only if ws too small.
// ---------------------------------------------------------------------------
__device__ __forceinline__ void gemm1_rc(
    const float* __restrict__ u, const unsigned short* __restrict__ BdKf,
    int b, int k, unsigned short* xs, unsigned short* ut, unsigned short* bb)
{
    const int tid = threadIdx.x;
    const int w = tid >> 6, l = tid & 63, lo = l & 31, hi = l >> 5;
    const int t0 = k * L_;
    f32x16 a00 = zero16(), a01 = zero16(), a10 = zero16(), a11 = zero16();
    for (int kk = 0; kk < 8; ++kk) {
        #pragma unroll
        for (int q = 0; q < 2; ++q) {
            const int i = q * 256 + tid, cl = i >> 4, t4 = i & 15;
            const float4 v = *(const float4*)(
                u + ((size_t)b * C_ + kk * 32 + cl) * T_ + t0 + t4 * 4);
            ut[(t4 * 4 + 0) * 40 + cl] = f2bf(v.x);
            ut[(t4 * 4 + 1) * 40 + cl] = f2bf(v.y);
            ut[(t4 * 4 + 2) * 40 + cl] = f2bf(v.z);
            ut[(t4 * 4 + 3) * 40 + cl] = f2bf(v.w);
        }
        {
            const unsigned short* src = BdKf + kk * 8192;
            #pragma unroll
            for (int q = 0; q < 4; ++q) {
                const int i16 = q * 256 + tid;
                *(int4*)(bb + i16 * 8) = *(const int4*)(src + i16 * 8);
            }
        }
        __syncthreads();
        #pragma unroll
        for (int s = 0; s < 2; ++s) {
            const short8 fa0 = *(const short8*)(ut + (0 * 32 + lo) * 40 + s * 16 + hi * 8);
            const short8 fa1 = *(const short8*)(ut + (1 * 32 + lo) * 40 + s * 16 + hi * 8);
            const short8 fb0 = *(const short8*)(bb + (((2 * w + 0) * 2 + s) * 64 + l) * 8);
            const short8 fb1 = *(const short8*)(bb + (((2 * w + 1) * 2 + s) * 64 + l) * 8);
            a00 = __builtin_amdgcn_mfma_f32_32x32x16_bf16(fa0, fb0, a00, 0, 0, 0);
            a01 = __builtin_amdgcn_mfma_f32_32x32x16_bf16(fa0, fb1, a01, 0, 0, 0);
            a10 = __builtin_amdgcn_mfma_f32_32x32x16_bf16(fa1, fb0, a10, 0, 0, 0);
            a11 = __builtin_amdgcn_mfma_f32_32x32x16_bf16(fa1, fb1, a11, 0, 0, 0);
        }
        __syncthreads();
    }
    #pragma unroll
    for (int tt = 0; tt < 2; ++tt)
        #pragma unroll
        for (int q = 0; q < 2; ++q) {
            const f32x16 a = (tt == 0) ? (q == 0 ? a00 : a01) : (q == 0 ? a10 : a11);
            const int n = (2 * w + q) * 32 + lo;
            #pragma unroll
            for (int g = 0; g < 4; ++g)
                #pragma unroll
                for (int p = 0; p < 2; ++p)
                    *(unsigned*)(xs + n * 66 + tt * 32 + hi * 4 + g * 8 + p * 2)
                        = f2bf(a[g * 4 + 2 * p]) | ((unsigned)f2bf(a[g * 4 + 2 * p + 1]) << 16);
        }
    __syncthreads();
}

__global__ __launch_bounds__(256) void k_phaseC_rc(
    const float* __restrict__ u, const unsigned short* __restrict__ BdKf,
    const unsigned short* __restrict__ CKf, const float* __restrict__ Ad,
    const float* __restrict__ carry, float* __restrict__ y)
{
    __shared__ __align__(16) unsigned short xs[16896];
    __shared__ __align__(16) unsigned short ut[2560];
    __shared__ __align__(16) unsigned short bb[8192];

    const int k = blockIdx.x, b = blockIdx.y;
    const int tid = threadIdx.x;
    const int w = tid >> 6, l = tid & 63, lo = l & 31, hi = l >> 5;
    const int t0 = k * L_;

    gemm1_rc(u, BdKf, b, k, xs, ut, bb);

    {
        const float a = Ad[tid];
        float s = carry[((size_t)k * B_ + b) * N_ + tid];
        float st[64];
        #pragma unroll
        for (int m = 0; m < 32; ++m) {
            const unsigned dw = *(const unsigned*)(xs + tid * 66 + 2 * m);
            s = fmaf(s, a, bf2f((unsigned short)(dw & 0xffff)));  st[2 * m] = s;
            s = fmaf(s, a, bf2f((unsigned short)(dw >> 16)));     st[2 * m + 1] = s;
        }
        __syncthreads();
        #pragma unroll
        for (int t = 0; t < 64; ++t) xs[t * 264 + tid] = f2bf(st[t]);
    }
    __syncthreads();

    f32x16 c00 = zero16(), c01 = zero16(), c10 = zero16(), c11 = zero16();
    for (int kk = 0; kk < 8; ++kk) {
        __syncthreads();
        {
            const unsigned short* src = CKf + kk * 8192;
            #pragma unroll
            for (int q = 0; q < 4; ++q) {
                const int i16 = q * 256 + tid;
                *(int4*)(bb + i16 * 8) = *(const int4*)(src + i16 * 8);
            }
        }
        __syncthreads();
        #pragma unroll
        for (int s = 0; s < 2; ++s) {
            const short8 fa0 = *(const short8*)(xs + (0 * 32 + lo) * 264 + kk * 32 + s * 16 + hi * 8);
            const short8 fa1 = *(const short8*)(xs + (1 * 32 + lo) * 264 + kk * 32 + s * 16 + hi * 8);
            const short8 fb0 = *(const short8*)(bb + (((2 * w + 0) * 2 + s) * 64 + l) * 8);
            const short8 fb1 = *(const short8*)(bb + (((2 * w + 1) * 2 + s) * 64 + l) * 8);
            c00 = __builtin_amdgcn_mfma_f32_32x32x16_bf16(fa0, fb0, c00, 0, 0, 0);
            c01 = __builtin_amdgcn_mfma_f32_32x32x16_bf16(fa0, fb1, c01, 0, 0, 0);
            c10 = __builtin_amdgcn_mfma_f32_32x32x16_bf16(fa1, fb0, c10, 0, 0, 0);
            c11 = __builtin_amdgcn_mfma_f32_32x32x16_bf16(fa1, fb1, c11, 0, 0, 0);
        }
    }

    #pragma unroll
    for (int tt = 0; tt < 2; ++tt)
        #pragma unroll
        for (int q = 0; q < 2; ++q) {
            const f32x16 a = (tt == 0) ? (q == 0 ? c00 : c01) : (q == 0 ? c10 : c11);
            const int o = (2 * w + q) * 32 + lo;
            float* yo = y + ((size_t)b * O_ + o) * T_ + t0 + tt * 32 + hi * 4;
            #pragma unroll
            for (int g = 0; g < 4; ++g) {
                float4 vv;
                vv.x = a[g * 4 + 0]; vv.y = a[g * 4 + 1];
                vv.z = a[g * 4 + 2]; vv.w = a[g * 4 + 3];
                *(float4*)(yo + g * 8) = vv;
            }
        }
}

// ---------------------------------------------------------------------------
extern "C" void kernel_launch(void* const* d_in, const int* in_sizes, int n_in,
                              void* d_out, int out_size, void* d_ws, size_t ws_size,
                              hipStream_t stream)
{
    const float* u  = (const float*)d_in[0];
    const float* rl = (const float*)d_in[1];
    const float* Bc = (const float*)d_in[2];
    const float* Cm = (const float*)d_in[3];
    float* y  = (float*)d_out;
    char*  ws = (char*)d_ws;

    float* Ad     = (float*)(ws + 0);
    float* AL     = (float*)(ws + 1024);
    float* p_last = (float*)(ws + 2048);
    float* carry  = (float*)(ws + 2048 + 2097152);
    unsigned short* BdKf = (unsigned short*)(ws + 2048 + 2 * 2097152);
    unsigned short* CKf  = (unsigned short*)(ws + 2048 + 2 * 2097152 + 131072);
    unsigned short* X    = (unsigned short*)(ws + 2048 + 2 * 2097152 + 2 * 131072);
    const size_t need = 2048 + 2ull * 2097152 + 2ull * 131072
                      + (size_t)NC_ * B_ * 32768;
    const int doX = (ws_size >= need) ? 1 : 0;

    k_prep  <<<dim3(256, 2),  dim3(256), 0, stream>>>(rl, Bc, Cm, Ad, AL, BdKf, CKf);
    k_phaseA<<<dim3(NC_, B_), dim3(256), 0, stream>>>(u, BdKf, Ad, p_last, X, doX);
    k_phaseB<<<dim3(B_),      dim3(256), 0, stream>>>(p_last, AL, carry);
    if (doX)
        k_phaseC<<<dim3(NC_, B_), dim3(256), 0, stream>>>(X, CKf, Ad, carry, y);
    else
        k_phaseC_rc<<<dim3(NC_, B_), dim3(256), 0, stream>>>(u, BdKf, CKf, Ad, carry, y);
}